// Round 6
// baseline (2428.089 us; speedup 1.0000x reference)
//
#include <hip/hip_runtime.h>
#include <hip/hip_bf16.h>

typedef __hip_bfloat16 bf16;
typedef short short8 __attribute__((ext_vector_type(8)));
typedef short short4v __attribute__((ext_vector_type(4)));
typedef float float4v __attribute__((ext_vector_type(4)));

#define D_ 256
#define NHEAD_ 8
#define DH_ 32
#define NQ_ 300
#define NLAYERS_ 6
#define DFF_ 1024
#define NCLS_ 80
#define BS_ 16
#define LM_ 8400
#define BN_ (BS_*NQ_)   // 4800

static __device__ __forceinline__ short f2bf(float x){
    union{float f; unsigned u;} v; v.f = x;
    unsigned r = v.u + 0x7FFF + ((v.u>>16)&1);
    return (short)(r>>16);
}
static __device__ __forceinline__ float bf2f(short s){
    union{unsigned u; float f;} v; v.u = ((unsigned)(unsigned short)s)<<16; return v.f;
}

// ================= value projection: A-in-registers, B-from-L2, no LDS/barriers =================
// memT: bf16 [134400][256]; WTall: 6 x [256][256] N-major at stride zWT;
// vb: [6][256]; values: 6 x [134400][256] bf16.
// grid = 2100 (one block per 64-row m-tile); per block 24 (z,ntile) combos reuse A regs.
__global__ __launch_bounds__(256) void valproj_kernel(
    const short* __restrict__ memT, const short* __restrict__ WTall, size_t zWT,
    const float* __restrict__ vb, short* __restrict__ values)
{
    int m0 = blockIdx.x*64;
    int tid = threadIdx.x, lane = tid&63, wave = tid>>6;
    int wm = (wave>>1)*32, wn = (wave&1)*32;
    int lr = lane&15, lq = lane>>4;
    // A fragments for the whole K=256: af[mi][t]
    short8 af[2][8];
    #pragma unroll
    for(int t=0;t<8;t++){
        #pragma unroll
        for(int mi=0;mi<2;mi++)
            af[mi][t] = *(const short8*)(memT + (size_t)(m0+wm+mi*16+lr)*256 + t*32 + lq*8);
    }
    short8 pb[2][2];
    #pragma unroll
    for(int ni=0;ni<2;ni++)
        pb[0][ni] = *(const short8*)(WTall + (size_t)(wn+ni*16+lr)*256 + lq*8);
    for(int c=0;c<24;c++){
        int zi = c>>2;
        int n0 = (c&3)*64;
        float4v acc[2][2];
        #pragma unroll
        for(int i=0;i<2;i++)
            #pragma unroll
            for(int j=0;j<2;j++){ acc[i][j].x=0.f; acc[i][j].y=0.f; acc[i][j].z=0.f; acc[i][j].w=0.f; }
        const short* wz = WTall + (size_t)zi*zWT;
        #pragma unroll
        for(int t=0;t<8;t++){
            const int cur = t&1;
            if(t<7){
                #pragma unroll
                for(int ni=0;ni<2;ni++)
                    pb[cur^1][ni] = *(const short8*)(wz + (size_t)(n0+wn+ni*16+lr)*256 + (t+1)*32 + lq*8);
            } else if(c<23){
                int c2 = c+1; int zi2 = c2>>2; int n02 = (c2&3)*64;
                const short* wz2 = WTall + (size_t)zi2*zWT;
                #pragma unroll
                for(int ni=0;ni<2;ni++)
                    pb[cur^1][ni] = *(const short8*)(wz2 + (size_t)(n02+wn+ni*16+lr)*256 + lq*8);
            }
            acc[0][0] = __builtin_amdgcn_mfma_f32_16x16x32_bf16(af[0][t], pb[cur][0], acc[0][0], 0,0,0);
            acc[0][1] = __builtin_amdgcn_mfma_f32_16x16x32_bf16(af[0][t], pb[cur][1], acc[0][1], 0,0,0);
            acc[1][0] = __builtin_amdgcn_mfma_f32_16x16x32_bf16(af[1][t], pb[cur][0], acc[1][0], 0,0,0);
            acc[1][1] = __builtin_amdgcn_mfma_f32_16x16x32_bf16(af[1][t], pb[cur][1], acc[1][1], 0,0,0);
        }
        const float* bb = vb + (size_t)zi*256;
        bf16* out = (bf16*)values + (size_t)zi*((size_t)134400*256);
        #pragma unroll
        for(int mi=0;mi<2;mi++){
            #pragma unroll
            for(int rr=0;rr<4;rr++){
                int gm = m0+wm+mi*16+lq*4+rr;
                #pragma unroll
                for(int ni=0;ni<2;ni++){
                    int gn = n0+wn+ni*16+lr;
                    out[(size_t)gm*256+gn] = __float2bfloat16(acc[mi][ni][rr]+bb[gn]);
                }
            }
        }
    }
}

// ================= fused pos MLP: pos = relu(refd@w1+b1)@w2 + b2 =================
// refd [4800][4] f32; w1 [4][512] f32; b1 [512]; w2T bf16 [256][512] (N-major); b2 [256].
// grid (4 n-tiles, 150 m-tiles of 32). hid staged bf16 in LDS; B frags direct from L2.
__global__ __launch_bounds__(256) void pos_mlp_kernel(
    const float* __restrict__ refd, const float* __restrict__ w1, const float* __restrict__ b1,
    const short* __restrict__ w2T, const float* __restrict__ b2, float* __restrict__ pos)
{
    __shared__ short hs[32*520];
    __shared__ float rs[32*4];
    int n0 = blockIdx.x*64, m0 = blockIdx.y*32;
    int tid = threadIdx.x;
    if(tid<128) rs[tid] = refd[(size_t)m0*4 + tid];
    __syncthreads();
    {
        int c0 = tid&255;
        float w1r[2][4], b1r[2];
        #pragma unroll
        for(int h=0;h<2;h++){
            int c = c0 + h*256;
            b1r[h] = b1[c];
            #pragma unroll
            for(int k=0;k<4;k++) w1r[h][k] = w1[k*512+c];
        }
        #pragma unroll 4
        for(int j=0;j<64;j++){
            int r = j>>1, h = j&1;
            int c = c0 + h*256;
            float v = 0.f;
            #pragma unroll
            for(int k=0;k<4;k++) v = fmaf(rs[r*4+k], w1r[h][k], v);
            v += b1r[h];
            hs[r*520+c] = f2bf(fmaxf(v,0.f));
        }
    }
    __syncthreads();
    int lane = tid&63, wave = tid>>6;
    int wm = (wave>>1)*16, wn = (wave&1)*32;
    int lr = lane&15, lq = lane>>4;
    float4v acc[2];
    #pragma unroll
    for(int j=0;j<2;j++){ acc[j].x=0.f; acc[j].y=0.f; acc[j].z=0.f; acc[j].w=0.f; }
    short8 pb[2][2];
    #pragma unroll
    for(int ni=0;ni<2;ni++)
        pb[0][ni] = *(const short8*)(w2T + (size_t)(n0+wn+ni*16+lr)*512 + lq*8);
    #pragma unroll
    for(int t=0;t<16;t++){
        const int cur = t&1;
        if(t<15){
            #pragma unroll
            for(int ni=0;ni<2;ni++)
                pb[cur^1][ni] = *(const short8*)(w2T + (size_t)(n0+wn+ni*16+lr)*512 + (t+1)*32 + lq*8);
        }
        short8 a0 = *(const short8*)(&hs[(wm+lr)*520 + t*32 + lq*8]);
        acc[0] = __builtin_amdgcn_mfma_f32_16x16x32_bf16(a0, pb[cur][0], acc[0], 0,0,0);
        acc[1] = __builtin_amdgcn_mfma_f32_16x16x32_bf16(a0, pb[cur][1], acc[1], 0,0,0);
    }
    #pragma unroll
    for(int rr=0;rr<4;rr++){
        int gm = m0+wm+lq*4+rr;
        #pragma unroll
        for(int ni=0;ni<2;ni++){
            int gn = n0+wn+ni*16+lr;
            pos[(size_t)gm*256+gn] = acc[ni][rr] + b2[gn];
        }
    }
}

// ================= MFMA bf16 GEMM (reg-staged double-buffered pipeline) =================
#define LSTR 40

template<int TM, int TN, bool ABF16, bool RELU, bool OUTBF16>
__global__ __launch_bounds__(256) void mfma_gemm_kernel(
    const void* __restrict__ Av, const void* __restrict__ A2v,
    const void* __restrict__ A3v, int nA2lim,
    const short* __restrict__ WT, size_t zWT,
    const float* __restrict__ b0, const float* __restrict__ b1,
    const float* __restrict__ b2, int ns1, int ns2, size_t zB,
    void* __restrict__ Cv, size_t zC, int M, int K, int N, int nxt)
{
    __shared__ short As[2][TM*LSTR];
    __shared__ short Bs[2][TN*LSTR];
    int zz, n0;
    if(nxt){ zz = blockIdx.x / nxt; n0 = (blockIdx.x % nxt)*TN; }
    else   { zz = blockIdx.z;       n0 = blockIdx.x*TN; }
    WT += (size_t)zz*zWT; b0 += (size_t)zz*zB; b1 += (size_t)zz*zB; b2 += (size_t)zz*zB;
    int tid = threadIdx.x;
    int lane = tid&63, wave = tid>>6;
    int m0 = blockIdx.y*TM;
    const int MI = TM/32;
    const int NI = TN/32;
    int wm = (wave>>1)*(TM/2), wn = (wave&1)*(TN/2);
    int lr = lane&15, lq = lane>>4;
    float4v acc[MI][NI];
    #pragma unroll
    for(int i=0;i<MI;i++)
        #pragma unroll
        for(int j=0;j<NI;j++){ acc[i][j].x=0.f; acc[i][j].y=0.f; acc[i][j].z=0.f; acc[i][j].w=0.f; }

    const float* Af; const float* Ad; const short* Ah;
    if(ABF16){ Ah = (const short*)Av; Af=nullptr; Ad=nullptr; }
    else {
        Af = (n0 < nA2lim)? (const float*)Av : (const float*)A3v;
        Ad = (n0 < nA2lim)? (const float*)A2v : nullptr;
        Ah = nullptr;
    }

    short8  rA16[ABF16? TM/64 : 1];
    float4v rAf [ABF16? 1 : TM/32];
    float4v rAd [ABF16? 1 : TM/32];
    short8  rB[TN/64];

    auto LOAD = [&](int k0){
        if constexpr(ABF16){
            #pragma unroll
            for(int it=0; it<TM/64; ++it){
                int idx=(it*256+tid)*8; int r=idx>>5, kk=idx&31; int gm=m0+r;
                short8 v = {};
                if(gm<M) v = *(const short8*)(Ah + (size_t)gm*K + (k0+kk));
                rA16[it]=v;
            }
        } else {
            #pragma unroll
            for(int it=0; it<TM/32; ++it){
                int idx=(it*256+tid)*4; int r=idx>>5, kk=idx&31; int gm=m0+r;
                float4v v; v.x=0.f;v.y=0.f;v.z=0.f;v.w=0.f;
                float4v w; w.x=0.f;w.y=0.f;w.z=0.f;w.w=0.f;
                if(gm<M){
                    v = *(const float4v*)(Af + (size_t)gm*K + (k0+kk));
                    if(Ad) w = *(const float4v*)(Ad + (size_t)gm*K + (k0+kk));
                }
                rAf[it]=v; rAd[it]=w;
            }
        }
        #pragma unroll
        for(int it=0; it<TN/64; ++it){
            int idx=(it*256+tid)*8; int r=idx>>5, kk=idx&31; int gn=n0+r;
            short8 v = {};
            if(gn<N) v = *(const short8*)(WT + (size_t)gn*K + (k0+kk));
            rB[it]=v;
        }
    };
    auto STORE = [&](int buf){
        if constexpr(ABF16){
            #pragma unroll
            for(int it=0; it<TM/64; ++it){
                int idx=(it*256+tid)*8; int r=idx>>5, kk=idx&31;
                *(short8*)(&As[buf][r*LSTR+kk]) = rA16[it];
            }
        } else {
            #pragma unroll
            for(int it=0; it<TM/32; ++it){
                int idx=(it*256+tid)*4; int r=idx>>5, kk=idx&31;
                float4v v = rAf[it];
                if(Ad){ v.x+=rAd[it].x; v.y+=rAd[it].y; v.z+=rAd[it].z; v.w+=rAd[it].w; }
                short4v h; h.x=f2bf(v.x); h.y=f2bf(v.y); h.z=f2bf(v.z); h.w=f2bf(v.w);
                *(short4v*)(&As[buf][r*LSTR+kk]) = h;
            }
        }
        #pragma unroll
        for(int it=0; it<TN/64; ++it){
            int idx=(it*256+tid)*8; int r=idx>>5, kk=idx&31;
            *(short8*)(&Bs[buf][r*LSTR+kk]) = rB[it];
        }
    };

    const int nt = K>>5;
    LOAD(0);
    STORE(0);
    __syncthreads();
    for(int t=0; t<nt; ++t){
        int cb = t&1;
        if(t+1<nt) LOAD((t+1)<<5);
        short8 af[MI], bfr[NI];
        #pragma unroll
        for(int mi=0;mi<MI;mi++) af[mi]  = *(const short8*)(&As[cb][(wm+mi*16+lr)*LSTR + lq*8]);
        #pragma unroll
        for(int ni=0;ni<NI;ni++) bfr[ni] = *(const short8*)(&Bs[cb][(wn+ni*16+lr)*LSTR + lq*8]);
        #pragma unroll
        for(int mi=0;mi<MI;mi++)
            #pragma unroll
            for(int ni=0;ni<NI;ni++)
                acc[mi][ni] = __builtin_amdgcn_mfma_f32_16x16x32_bf16(af[mi], bfr[ni], acc[mi][ni], 0,0,0);
        if(t+1<nt){
            STORE(cb^1);
            __syncthreads();
        }
    }
    float* Cf=(float*)Cv + (size_t)zz*zC; bf16* Ch=(bf16*)Cv + (size_t)zz*zC;
    #pragma unroll
    for(int mi=0;mi<MI;mi++){
        #pragma unroll
        for(int r=0;r<4;r++){
            int gm = m0+wm+mi*16+lq*4+r;
            if(gm>=M) continue;
            #pragma unroll
            for(int ni=0;ni<NI;ni++){
                int gn = n0+wn+ni*16+lr;
                if(gn>=N) continue;
                float bv = (gn<ns1)? b0[gn] : ((gn<ns2)? b1[gn-ns1] : b2[gn-ns2]);
                float v = acc[mi][ni][r] + bv;
                if(RELU) v = fmaxf(v,0.f);
                if(OUTBF16) Ch[(size_t)gm*N+gn]=__float2bfloat16(v);
                else        Cf[(size_t)gm*N+gn]=v;
            }
        }
    }
}

// ================= fused MHA (union LDS, vectorized staging, bf16 out) =================
__global__ __launch_bounds__(256) void fused_mha_kernel(
    const float* __restrict__ QKV, short* __restrict__ O)
{
    const int ld = 768;
    int bh = blockIdx.y; int b = bh>>3, h = bh&7;
    int q0 = blockIdx.x*64;
    __shared__ short lds[31104];   // 62208 B
    short* Vts = lds;              // 32 x 324
    short* Qs  = lds + 10368;      // 64 x 36
    short* Ks  = lds + 12672;      // 304 x 36
    short* Ps  = lds + 10368;      // 64 x 324, overlays Qs+Ks after S-phase
    int tid = threadIdx.x;
    for(int idx=tid; idx<64*8; idx+=256){
        int r=idx>>3, c4=(idx&7)*4; int gq=q0+r;
        float4v v; v.x=0.f;v.y=0.f;v.z=0.f;v.w=0.f;
        if(gq<NQ_) v = *(const float4v*)(QKV + ((size_t)(b*NQ_+gq))*ld + h*DH_ + c4);
        short4v h4; h4.x=f2bf(v.x);h4.y=f2bf(v.y);h4.z=f2bf(v.z);h4.w=f2bf(v.w);
        *(short4v*)(Qs + r*36 + c4) = h4;
    }
    for(int idx=tid; idx<304*8; idx+=256){
        int r=idx>>3, c4=(idx&7)*4;
        float4v v; v.x=0.f;v.y=0.f;v.z=0.f;v.w=0.f;
        if(r<NQ_) v = *(const float4v*)(QKV + 256 + ((size_t)(b*NQ_+r))*ld + h*DH_ + c4);
        short4v h4; h4.x=f2bf(v.x);h4.y=f2bf(v.y);h4.z=f2bf(v.z);h4.w=f2bf(v.w);
        *(short4v*)(Ks + r*36 + c4) = h4;
    }
    for(int idx=tid; idx<320*8; idx+=256){
        int r=idx>>3, c4=(idx&7)*4;
        float4v v; v.x=0.f;v.y=0.f;v.z=0.f;v.w=0.f;
        if(r<NQ_) v = *(const float4v*)(QKV + 512 + ((size_t)(b*NQ_+r))*ld + h*DH_ + c4);
        Vts[(c4+0)*324+r]=f2bf(v.x); Vts[(c4+1)*324+r]=f2bf(v.y);
        Vts[(c4+2)*324+r]=f2bf(v.z); Vts[(c4+3)*324+r]=f2bf(v.w);
    }
    __syncthreads();

    int lane = tid&63, wave = tid>>6;
    int lr = lane&15, lq = lane>>4;
    int mrow = wave*16;
    const float scale = 0.17677669529663687f;

    float4v acc[19];
    #pragma unroll
    for(int t=0;t<19;t++){ acc[t].x=0.f; acc[t].y=0.f; acc[t].z=0.f; acc[t].w=0.f; }
    short8 afrag = *(const short8*)(&Qs[(mrow+lr)*36 + lq*8]);
    #pragma unroll
    for(int t=0;t<19;t++){
        short8 bfrag = *(const short8*)(&Ks[(t*16+lr)*36 + lq*8]);
        acc[t] = __builtin_amdgcn_mfma_f32_16x16x32_bf16(afrag, bfrag, acc[t], 0,0,0);
    }
    __syncthreads();   // Qs/Ks dead; Ps overlay becomes writable

    for(int idx=tid; idx<64*16; idx+=256){
        int r=idx>>4, c=idx&15;
        Ps[r*324 + 304 + c]=0;
    }
    #pragma unroll
    for(int t=0;t<19;t++){
        #pragma unroll
        for(int r=0;r<4;r++) acc[t][r] *= scale;
    }
    if(lr>=12){
        #pragma unroll
        for(int r=0;r<4;r++) acc[18][r] = -1e30f;
    }
    float mx[4];
    #pragma unroll
    for(int r=0;r<4;r++){
        float m = acc[0][r];
        #pragma unroll
        for(int t=1;t<19;t++) m = fmaxf(m, acc[t][r]);
        m = fmaxf(m, __shfl_xor(m,1)); m = fmaxf(m, __shfl_xor(m,2));
        m = fmaxf(m, __shfl_xor(m,4)); m = fmaxf(m, __shfl_xor(m,8));
        mx[r]=m;
    }
    float sum[4] = {0.f,0.f,0.f,0.f};
    #pragma unroll
    for(int t=0;t<19;t++){
        #pragma unroll
        for(int r=0;r<4;r++){
            float p = __expf(acc[t][r]-mx[r]);
            acc[t][r]=p; sum[r]+=p;
        }
    }
    #pragma unroll
    for(int r=0;r<4;r++){
        float s = sum[r];
        s += __shfl_xor(s,1); s += __shfl_xor(s,2);
        s += __shfl_xor(s,4); s += __shfl_xor(s,8);
        sum[r] = 1.f/s;
    }
    #pragma unroll
    for(int t=0;t<19;t++){
        #pragma unroll
        for(int r=0;r<4;r++){
            Ps[(mrow + lq*4 + r)*324 + t*16 + lr] = f2bf(acc[t][r]*sum[r]);
        }
    }
    __syncthreads();
    float4v oacc[2];
    oacc[0].x=0.f;oacc[0].y=0.f;oacc[0].z=0.f;oacc[0].w=0.f;
    oacc[1]=oacc[0];
    #pragma unroll
    for(int kc=0;kc<10;kc++){
        short8 pa = *(const short8*)(&Ps[(mrow+lr)*324 + kc*32 + lq*8]);
        #pragma unroll
        for(int n=0;n<2;n++){
            short8 vb = *(const short8*)(&Vts[(n*16+lr)*324 + kc*32 + lq*8]);
            oacc[n] = __builtin_amdgcn_mfma_f32_16x16x32_bf16(pa, vb, oacc[n], 0,0,0);
        }
    }
    #pragma unroll
    for(int n=0;n<2;n++){
        #pragma unroll
        for(int r=0;r<4;r++){
            int gq = q0 + mrow + lq*4 + r;
            if(gq<NQ_)
                O[((size_t)(b*NQ_+gq))*D_ + h*DH_ + n*16 + lr] = f2bf(oacc[n][r]);
        }
    }
}

// ============== all-weights transpose f32[K][N] -> bf16[N][K] ==============
#define NTD 74
struct TD { const float* src; unsigned dstoff; int K, N, base; };
struct TAll { TD d[NTD]; };

__global__ __launch_bounds__(256) void transpose_all_kernel(TAll p, short* __restrict__ WTb){
    int blk = blockIdx.x;
    int di = 0;
    #pragma unroll 1
    for(int i=0;i<NTD;i++){ if(blk >= p.d[i].base) di = i; }
    TD d = p.d[di];
    int rel = blk - d.base;
    int ntx = (d.N+31)/32;
    int tn = (rel % ntx)*32, tk = (rel / ntx)*32;
    __shared__ float t[32][33];
    int tx = threadIdx.x&31, ty = threadIdx.x>>5;
    for(int i=0;i<32;i+=8){
        int k = tk+ty+i, n = tn+tx;
        t[ty+i][tx] = (k<d.K && n<d.N)? d.src[(size_t)k*d.N+n] : 0.f;
    }
    __syncthreads();
    short* out = WTb + d.dstoff;
    for(int i=0;i<32;i+=8){
        int n = tn+ty+i, k = tk+tx;
        if(n<d.N && k<d.K) out[(size_t)n*d.K+k] = f2bf(t[tx][ty+i]);
    }
}

// ================= SIMT GEMM (tiny K/N; optional fused bbox-update epilogue) =================
template<bool RELU, bool BBOX>
__global__ __launch_bounds__(256) void gemm_kernel(
    const float* __restrict__ A, const float* __restrict__ W,
    const float* __restrict__ bias, float* __restrict__ Cf,
    int M, int K, int N)
{
    __shared__ float As[16][68];
    __shared__ float Bs[16][68];
    int tid = threadIdx.x;
    int m0 = blockIdx.y*64, n0 = blockIdx.x*64;
    int tm = tid>>4, tn = tid&15;
    float acc[4][4] = {};
    int lam = tid>>2;
    int lak = (tid&3)*4;
    int lbk = tid>>4;
    int lbn = (tid&15)*4;
    for(int k0=0;k0<K;k0+=16){
        {
            int m = m0+lam;
            #pragma unroll
            for(int j=0;j<4;j++){
                int k = k0+lak+j;
                float v=0.f;
                if(m<M && k<K) v = A[(size_t)m*K+k];
                As[lak+j][lam]=v;
            }
        }
        {
            int k = k0+lbk;
            #pragma unroll
            for(int j=0;j<4;j++){
                int n = n0+lbn+j;
                float v=0.f;
                if(k<K && n<N) v = W[(size_t)k*N+n];
                Bs[lbk][lbn+j]=v;
            }
        }
        __syncthreads();
        #pragma unroll
        for(int kk=0;kk<16;kk++){
            float a[4], bb[4];
            #pragma unroll
            for(int i=0;i<4;i++) a[i]=As[kk][tm*4+i];
            #pragma unroll
            for(int j=0;j<4;j++) bb[j]=Bs[kk][tn*4+j];
            #pragma unroll
            for(int i=0;i<4;i++)
                #pragma unroll
                for(int j=0;j<4;j++) acc[i][j] += a[i]*bb[j];
        }
        __syncthreads();
    }
    #pragma unroll
    for(int i=0;i<4;i++){
        int m=m0+tm*4+i; if(m>=M) continue;
        #pragma unroll
        for(int j=0;j<4;j++){
            int n=n0+tn*4+j; if(n>=N) continue;
            float v = acc[i][j] + bias[n];
            if(BBOX){
                float x = Cf[(size_t)m*N+n];
                x = fminf(fmaxf(x,0.f),1.f);
                float num = fmaxf(x,1e-5f), den = fmaxf(1.f-x,1e-5f);
                float nd = v + logf(num/den);
                Cf[(size_t)m*N+n] = 1.f/(1.f+expf(-nd));
            } else {
                if(RELU) v = fmaxf(v,0.f);
                Cf[(size_t)m*N+n]=v;
            }
        }
    }
}

// ---------------- small elementwise kernels ----------------
__global__ void copy_kernel(const float* __restrict__ a, float* __restrict__ o, int n){
    int i = blockIdx.x*blockDim.x+threadIdx.x;
    if(i<n) o[i]=a[i];
}
__global__ void cvt_f32_bf16_kernel(const float* __restrict__ a, short* __restrict__ o, int n4){
    int i = blockIdx.x*blockDim.x+threadIdx.x;
    if(i<n4){
        float4v v = *(const float4v*)(a + (size_t)i*4);
        short4v h; h.x=f2bf(v.x); h.y=f2bf(v.y); h.z=f2bf(v.z); h.w=f2bf(v.w);
        *(short4v*)(o + (size_t)i*4) = h;
    }
}
__global__ void sigmoid_init_kernel(const float* __restrict__ a, float* __restrict__ o, int n){
    int i = blockIdx.x*blockDim.x+threadIdx.x;
    if(i<n){ float x=a[i]; o[i]=1.f/(1.f+expf(-x)); }
}
__global__ void write_out_kernel(const float* __restrict__ refd, const float* __restrict__ logits, float* __restrict__ out){
    int i = blockIdx.x*blockDim.x+threadIdx.x;
    if(i<BN_*4) out[i]=refd[i];
    else if(i<BN_*4+BN_*NCLS_) out[i]=logits[i-BN_*4];
}

// ---------------- layernorm with residual (t2 bf16), optional bf16 copy-out ----------------
__global__ __launch_bounds__(256) void ln_residual_kernel(
    float* __restrict__ cur, const short* __restrict__ t2b,
    const float* __restrict__ g, const float* __restrict__ b,
    short* __restrict__ cb)
{
    int row = blockIdx.x; int c = threadIdx.x;
    size_t idx = (size_t)row*D_+c;
    float x = cur[idx] + bf2f(t2b[idx]);
    float v1 = x, v2 = x*x;
    #pragma unroll
    for(int o=32;o>0;o>>=1){ v1 += __shfl_down(v1,o,64); v2 += __shfl_down(v2,o,64); }
    __shared__ float s1[4], s2[4], st[2];
    int wid=c>>6, lane=c&63;
    if(lane==0){ s1[wid]=v1; s2[wid]=v2; }
    __syncthreads();
    if(c==0){
        float a=0,d=0;
        #pragma unroll
        for(int i=0;i<4;i++){a+=s1[i]; d+=s2[i];}
        st[0]=a/(float)D_; st[1]=d/(float)D_;
    }
    __syncthreads();
    float m=st[0], var=st[1]-m*m;
    float y = (x-m)*rsqrtf(var+1e-5f)*g[c] + b[c];
    cur[idx]=y;
    if(cb) cb[idx]=f2bf(y);
}

// ---------------- deformable sampling (fused attw softmax, bf16 out) ----------------
__global__ __launch_bounds__(256) void deform_sample_kernel(
    const float* __restrict__ refd, const float* __restrict__ oab,
    const bf16* __restrict__ value, short* __restrict__ outacc)
{
    int row = blockIdx.x; int b = row/NQ_;
    int tid = threadIdx.x; int h = tid>>5, c = tid&31;
    __shared__ float so[192], sa[96], sr[4];
    if(tid<192) so[tid]=oab[(size_t)row*288+tid];
    if(tid<96)  sa[tid]=oab[(size_t)row*288+192+tid];
    if(tid<4)   sr[tid]=refd[(size_t)row*4+tid];
    __syncthreads();
    if(tid<8){
        float* p = sa + tid*12;
        float m=-1e30f;
        #pragma unroll
        for(int i2=0;i2<12;i2++) m=fmaxf(m,p[i2]);
        float s=0.f;
        #pragma unroll
        for(int i2=0;i2<12;i2++){ float e=__expf(p[i2]-m); p[i2]=e; s+=e; }
        float inv=1.f/s;
        #pragma unroll
        for(int i2=0;i2<12;i2++) p[i2]*=inv;
    }
    __syncthreads();
    float cx=sr[0], cy=sr[1], rw=sr[2], rh=sr[3];
    const int HS[3]={80,40,20}, WS[3]={80,40,20}, ST[3]={0,6400,8000};
    float acc=0.f;
    const bf16* vb = value + (size_t)b*LM_*D_ + h*DH_ + c;
    for(int lv=0;lv<3;lv++){
        int Hl=HS[lv], Wl=WS[lv], st=ST[lv];
        #pragma unroll
        for(int pt=0;pt<4;pt++){
            int oi = ((h*3+lv)*4+pt)*2;
            float ox=so[oi], oy=so[oi+1];
            float wa=sa[h*12+lv*4+pt];
            float lx = cx + ox*0.25f*rw*0.5f;
            float ly = cy + oy*0.25f*rh*0.5f;
            float x = lx*(float)Wl - 0.5f, y = ly*(float)Hl - 0.5f;
            float x0f=floorf(x), y0f=floorf(y);
            float wx=x-x0f, wy=y-y0f;
            int x0=(int)x0f, y0=(int)y0f;
            #pragma unroll
            for(int dy=0;dy<2;dy++){
                #pragma unroll
                for(int dx=0;dx<2;dx++){
                    int xi=x0+dx, yi=y0+dy;
                    if(xi>=0 && xi<Wl && yi>=0 && yi<Hl){
                        float w = (dx? wx : 1.f-wx)*(dy? wy : 1.f-wy);
                        int lin = yi*Wl+xi;
                        acc += __bfloat162float(vb[(size_t)(st+lin)*D_]) * (w*wa);
                    }
                }
            }
        }
    }
    outacc[(size_t)row*D_+tid]=f2bf(acc);
}

// ---------------- host helpers ----------------
static void gemm_bbox(const float*A, const float*W, const float*b, float*refd,
                      int M,int K,int N, hipStream_t s){
    dim3 g((N+63)/64,(M+63)/64);
    gemm_kernel<false,true><<<g,256,0,s>>>(A,W,b,refd,M,K,N);
}
// tail GEMM dispatcher: TM=64, TN=64
static void g64x(const void*A, const void*A2, const void*A3, int nA2lim,
                 const short*WT, const float*b0, const float*b1, const float*b2,
                 int ns1, int ns2, void*C, int M,int K,int N,
                 bool abf16, bool relu, bool outbf, hipStream_t s){
    dim3 g((N+63)/64,(M+63)/64,1);
    #define CALLG(AB,RL,OB) mfma_gemm_kernel<64,64,AB,RL,OB><<<g,256,0,s>>>(A,A2,A3,nA2lim,WT,0,b0,b1,b2,ns1,ns2,0,C,0,M,K,N,0)
    if(abf16){
        if(relu){ if(outbf) CALLG(true,true,true);  else CALLG(true,true,false); }
        else    { if(outbf) CALLG(true,false,true); else CALLG(true,false,false); }
    } else {
        if(relu){ if(outbf) CALLG(false,true,true);  else CALLG(false,true,false); }
        else    { if(outbf) CALLG(false,false,true); else CALLG(false,false,false); }
    }
    #undef CALLG
}
static void g64(const float*A, const float*A2, const float*A3, int nA2lim,
                const short*WT, const float*b0, const float*b1, const float*b2,
                int ns1, int ns2, void*C, int M,int K,int N,
                bool relu, bool outbf, hipStream_t s){
    g64x(A,A2,A3,nA2lim,WT,b0,b1,b2,ns1,ns2,C,M,K,N,false,relu,outbf,s);
}
static void g64b(const short*A, const short*WT, const float*b, void*C,
                 int M,int K,int N, hipStream_t s){
    g64x(A,nullptr,nullptr,1<<30,WT,b,b,b,N,N+1,C,M,K,N,true,false,true,s);
}
static int ntiles(int K,int N){ return ((N+31)/32)*((K+31)/32); }

extern "C" void kernel_launch(void* const* d_in, const int* in_sizes, int n_in,
                              void* d_out, int out_size, void* d_ws, size_t ws_size,
                              hipStream_t stream) {
    const float* tgt   = (const float*)d_in[0];
    const float* rpu   = (const float*)d_in[1];
    const float* mem   = (const float*)d_in[2];
    const float* sa_wq = (const float*)d_in[3];
    const float* sa_wk = (const float*)d_in[4];
    const float* sa_wv = (const float*)d_in[5];
    const float* sa_wo = (const float*)d_in[6];
    const float* val_w = (const float*)d_in[7];
    const float* out_w = (const float*)d_in[8];
    const float* bb_w1 = (const float*)d_in[9];
    const float* bb_w2 = (const float*)d_in[10];
    const float* sa_bq = (const float*)d_in[11];
    const float* sa_bk = (const float*)d_in[12];
    const float* sa_bv = (const float*)d_in[13];
    const float* sa_bo = (const float*)d_in[14];
    const float* ln1_b = (const float*)d_in[15];
    const float* ln2_b = (const float*)d_in[16];
    const float* ln3_b = (const float*)d_in[17];
    const float* val_b = (const float*)d_in[18];
    const float* out_b = (const float*)d_in[19];
    const float* ffn_b2= (const float*)d_in[20];
    const float* bb_b1 = (const float*)d_in[21];
    const float* bb_b2 = (const float*)d_in[22];
    const float* ln1_g = (const float*)d_in[23];
    const float* ln2_g = (const float*)d_in[24];
    const float* ln3_g = (const float*)d_in[25];
    const float* off_w = (const float*)d_in[26];
    const float* off_b = (const float*)d_in[27];
    const float* attw_w= (const float*)d_in[28];
    const float* attw_b= (const float*)d_in[29];
    const float* ffn_w1= (const float*)d_in[30];
    const float* ffn_b1= (const float*)d_in[31];
    const float* ffn_w2= (const float*)d_in[32];
    const float* bb_w3 = (const float*)d_in[33];
    const float* bb_b3 = (const float*)d_in[34];
    const float* sc_w  = (const float*)d_in[35];
    const float* sc_b  = (const float*)d_in[36];
    const float* qp_w1 = (const float*)d_in[37];
    const float* qp_b1 = (const float*)d_in[38];
    const float* qp_w2 = (const float*)d_in[39];
    const float* qp_b2 = (const float*)d_in[40];

    const size_t BND = (size_t)BN_*D_;          // 1,228,800
    const size_t USZ = (size_t)BN_*DFF_;        // 4,915,200 floats (union)
    const size_t LMD = (size_t)BS_*LM_*D_;      // 34,406,400
    const size_t LSZ = 1122304;                 // WT shorts per layer

    float* ws   = (float*)d_ws;
    float* cur  = ws;
    float* pos  = cur + BND;
    float* refd = pos + BND;
    float* U    = refd + (size_t)BN_*4;
    short* tmp16 = (short*)(U + USZ);
    short* t216  = tmp16 + BND;
    short* WT    = t216 + BND;
    short* qp2T  = WT + 6*LSZ;
    short* scT   = qp2T + 131072;
    short* X     = scT + 20480;
    // U aliases (phase-disjoint)
    float* QKVh   = U;
    float* offsb  = U;
    short* ffnh16 = (short*)U;
    short* bb1b   = (short*)U;
    float* bb2    = U + BND;
    float* logitsb= U;
    short* curb = tmp16;

    size_t offX = (size_t)((char*)X - (char*)d_ws);
    int vmode;
    if(ws_size >= offX + 7*LMD*2)      vmode = 3;
    else if(ws_size >= offX + 6*LMD*2) vmode = 2;
    else if(ws_size >= offX + 4*LMD)   vmode = 1;
    else                               vmode = 0;
    short* memT   = X;
    short* values = (vmode==3)? X + LMD : X;
    short* value1 = X + LMD;
    short* value0 = X;

    const int nBN_D = (int)BND;
    copy_kernel<<<(nBN_D+255)/256,256,0,stream>>>(tgt, cur, nBN_D);
    sigmoid_init_kernel<<<(BN_*4+255)/256,256,0,stream>>>(rpu, refd, BN_*4);
    if(vmode==1 || vmode==3){
        int n4 = (int)(LMD/4);
        cvt_f32_bf16_kernel<<<(n4+255)/256,256,0,stream>>>(mem, memT, n4);
    }

    // ---- transpose ALL weights upfront (one launch) ----
    {
        TAll tp; int base=0; int di=0;
        const size_t offs[12] = { 0,65536,131072,196608,262144,327680,
                                  393216,442368,466944,729088,991232,1056768 };
        const int Ks[12] = { 256,256,256,256,256,256,256,256,256,1024,256,256 };
        const int Ns[12] = { 256,256,256,256,256,256,192,96,1024,256,256,256 };
        for(int l=0;l<NLAYERS_;l++){
            const float* srcs[12] = { sa_wq+(size_t)l*D_*D_, sa_wk+(size_t)l*D_*D_, sa_wv+(size_t)l*D_*D_,
                                      sa_wo+(size_t)l*D_*D_, val_w+(size_t)l*D_*D_, out_w+(size_t)l*D_*D_,
                                      off_w+(size_t)l*D_*192, attw_w+(size_t)l*D_*96,
                                      ffn_w1+(size_t)l*D_*DFF_, ffn_w2+(size_t)l*DFF_*D_,
                                      bb_w1+(size_t)l*D_*D_, bb_w2+(size_t)l*D_*D_ };
            for(int j=0;j<12;j++){
                tp.d[di] = { srcs[j], (unsigned)(l*LSZ + offs[j]), Ks[j], Ns[j], base };
                base += ntiles(Ks[j],Ns[j]); di++;
            }
        }
        tp.d[di] = { qp_w2, (unsigned)(6*LSZ), 512, 256, base }; base += ntiles(512,256); di++;
        tp.d[di] = { sc_w + (size_t)(NLAYERS_-1)*D_*NCLS_, (unsigned)(6*LSZ+131072), 256, 80, base }; base += ntiles(256,80); di++;
        transpose_all_kernel<<<base,256,0,stream>>>(tp, WT);
    }

    // ---- value projections ----
    if(vmode==3){
        valproj_kernel<<<2100,256,0,stream>>>(memT, WT+262144, LSZ, val_b, values);
    } else if(vmode==2){
        dim3 g(12,1050,1);
        mfma_gemm_kernel<128,128,false,false,true><<<g,256,0,stream>>>(
            mem,nullptr,mem,1<<30, WT+262144, LSZ,
            val_b,val_b,val_b, 256,257, 256, values, LMD, BS_*LM_, D_, D_, 2);
    }

    for(int i=0;i<NLAYERS_;i++){
        const bf16* value_i;
        if(vmode>=2) value_i = (const bf16*)(values + (size_t)i*LMD);
        else {
            dim3 g(2,1050,1);
            if(vmode==1){
                mfma_gemm_kernel<128,128,true,false,true><<<g,256,0,stream>>>(
                    memT,nullptr,nullptr,1<<30, WT+i*LSZ+262144, 0,
                    val_b+(size_t)i*D_,val_b,val_b, 256,257, 0, value1, 0, BS_*LM_, D_, D_, 0);
                value_i = (const bf16*)value1;
            } else {
                mfma_gemm_kernel<128,128,false,false,true><<<g,256,0,stream>>>(
                    mem,nullptr,mem,1<<30, WT+i*LSZ+262144, 0,
                    val_b+(size_t)i*D_,val_b,val_b, 256,257, 0, value0, 0, BS_*LM_, D_, D_, 0);
                value_i = (const bf16*)value0;
            }
        }
        // pos = MLP2(refd) — fused single kernel
        pos_mlp_kernel<<<dim3(4,150),256,0,stream>>>(refd, qp_w1, qp_b1, qp2T, qp_b2, pos);
        // QKV fused: Q,K from cur+pos (n<512), V from cur
        g64(cur, pos, cur, 512, WT+i*LSZ,
            sa_bq+(size_t)i*D_, sa_bk+(size_t)i*D_, sa_bv+(size_t)i*D_, 256, 512,
            QKVh, BN_, D_, 768, false,false, stream);
        {
            dim3 g((NQ_+63)/64, BS_*NHEAD_);
            fused_mha_kernel<<<g,256,0,stream>>>(QKVh, tmp16);
        }
        g64b(tmp16, WT+i*LSZ+196608, sa_bo+(size_t)i*D_, t216, BN_, D_, D_, stream);
        ln_residual_kernel<<<BN_,256,0,stream>>>(cur, t216, ln1_g+(size_t)i*D_, ln1_b+(size_t)i*D_, nullptr);
        // deformable attention: fused off|attw projection from cur+pos
        g64(cur, pos, cur, 1<<30, WT+i*LSZ+393216,
            off_b+(size_t)i*192, attw_b+(size_t)i*96, attw_b+(size_t)i*96, 192, 288,
            offsb, BN_, D_, 288, false,false, stream);
        deform_sample_kernel<<<BN_,256,0,stream>>>(refd, offsb, value_i, tmp16);
        g64b(tmp16, WT+i*LSZ+327680, out_b+(size_t)i*D_, t216, BN_, D_, D_, stream);
        ln_residual_kernel<<<BN_,256,0,stream>>>(cur, t216, ln2_g+(size_t)i*D_, ln2_b+(size_t)i*D_, curb);
        // FFN: A = bf16 cur (from ln2), hidden bf16, FFN2 bf16-A
        g64x(curb,nullptr,nullptr,1<<30, WT+i*LSZ+466944, ffn_b1+(size_t)i*DFF_,ffn_b1,ffn_b1, DFF_,DFF_+1,
             ffnh16, BN_, D_, DFF_, true,true,true, stream);
        g64x(ffnh16,nullptr,nullptr,1<<30, WT+i*LSZ+729088, ffn_b2+(size_t)i*D_,ffn_b2,ffn_b2, 256,257,
             t216, BN_, DFF_, D_, true,false,true, stream);
        ln_residual_kernel<<<BN_,256,0,stream>>>(cur, t216, ln3_g+(size_t)i*D_, ln3_b+(size_t)i*D_, curb);
        // bbox head: bf16-A chain, bb3+bbox_update fused
        g64x(curb,nullptr,nullptr,1<<30, WT+i*LSZ+991232, bb_b1+(size_t)i*D_,bb_b1,bb_b1, 256,257,
             bb1b, BN_, D_, D_, true,true,true, stream);
        g64x(bb1b,nullptr,nullptr,1<<30, WT+i*LSZ+1056768, bb_b2+(size_t)i*D_,bb_b2,bb_b2, 256,257,
             bb2, BN_, D_, D_, true,true,false, stream);
        gemm_bbox(bb2, bb_w3+(size_t)i*D_*4, bb_b3+(size_t)i*4, refd, BN_, D_, 4, stream);
    }
    // final score GEMM: A = bf16 cur (curb from layer-5 ln3)
    g64x(curb,nullptr,nullptr,1<<30, scT, sc_b+(size_t)(NLAYERS_-1)*NCLS_,sc_b,sc_b, NCLS_,NCLS_+1,
         logitsb, BN_, D_, NCLS_, true,false,false, stream);
    int tot = BN_*4 + BN_*NCLS_;
    write_out_kernel<<<(tot+255)/256,256,0,stream>>>(refd, logitsb, (float*)d_out);
}

// Round 7
// 2425.270 us; speedup vs baseline: 1.0012x; 1.0012x over previous
//
#include <hip/hip_runtime.h>
#include <hip/hip_bf16.h>

typedef __hip_bfloat16 bf16;
typedef short short8 __attribute__((ext_vector_type(8)));
typedef short short4v __attribute__((ext_vector_type(4)));
typedef float float4v __attribute__((ext_vector_type(4)));

#define D_ 256
#define NHEAD_ 8
#define DH_ 32
#define NQ_ 300
#define NLAYERS_ 6
#define DFF_ 1024
#define NCLS_ 80
#define BS_ 16
#define LM_ 8400
#define BN_ (BS_*NQ_)   // 4800

static __device__ __forceinline__ short f2bf(float x){
    union{float f; unsigned u;} v; v.f = x;
    unsigned r = v.u + 0x7FFF + ((v.u>>16)&1);
    return (short)(r>>16);
}
static __device__ __forceinline__ float bf2f(short s){
    union{unsigned u; float f;} v; v.u = ((unsigned)(unsigned short)s)<<16; return v.f;
}

// ================= value projection: A-in-registers, B-from-L2, ring-prefetch =================
// memT: bf16 [134400][256]; WTall: 6 x [256][256] N-major at stride zWT;
// vb: [6][256]; values: 6 x [134400][256] bf16.
// grid = 2100 (one block per 64-row m-tile). 192 flattened steps = 24 (z,n) combos x 8 K-steps.
// B-frags ring-prefetched PF=4 steps ahead (8 loads in flight) to cover L2 latency.
__global__ __launch_bounds__(256) void valproj_kernel(
    const short* __restrict__ memT, const short* __restrict__ WTall, size_t zWT,
    const float* __restrict__ vb, short* __restrict__ values)
{
    int m0 = blockIdx.x*64;
    int tid = threadIdx.x, lane = tid&63, wave = tid>>6;
    int wm = (wave>>1)*32, wn = (wave&1)*32;
    int lr = lane&15, lq = lane>>4;
    // A fragments for the whole K=256
    short8 af[2][8];
    #pragma unroll
    for(int t=0;t<8;t++){
        #pragma unroll
        for(int mi=0;mi<2;mi++)
            af[mi][t] = *(const short8*)(memT + (size_t)(m0+wm+mi*16+lr)*256 + t*32 + lq*8);
    }
    const int PF = 4;
    short8 pb[PF][2];
    // step s: zi=s>>5, n0=((s>>3)&3)*64, t=s&7
    #pragma unroll
    for(int s=0;s<PF;s++){
        int zi=s>>5, n0=((s>>3)&3)*64, t=s&7;
        const short* wz = WTall + (size_t)zi*zWT;
        pb[s][0] = *(const short8*)(wz + (size_t)(n0+wn+lr)*256 + t*32 + lq*8);
        pb[s][1] = *(const short8*)(wz + (size_t)(n0+wn+16+lr)*256 + t*32 + lq*8);
    }
    float4v acc[2][2];
    #pragma unroll
    for(int s=0;s<192;s++){
        const int slot = s&(PF-1);
        const int t = s&7;
        if(t==0){
            #pragma unroll
            for(int i=0;i<2;i++)
                #pragma unroll
                for(int j=0;j<2;j++){ acc[i][j].x=0.f; acc[i][j].y=0.f; acc[i][j].z=0.f; acc[i][j].w=0.f; }
        }
        acc[0][0] = __builtin_amdgcn_mfma_f32_16x16x32_bf16(af[0][t], pb[slot][0], acc[0][0], 0,0,0);
        acc[0][1] = __builtin_amdgcn_mfma_f32_16x16x32_bf16(af[0][t], pb[slot][1], acc[0][1], 0,0,0);
        acc[1][0] = __builtin_amdgcn_mfma_f32_16x16x32_bf16(af[1][t], pb[slot][0], acc[1][0], 0,0,0);
        acc[1][1] = __builtin_amdgcn_mfma_f32_16x16x32_bf16(af[1][t], pb[slot][1], acc[1][1], 0,0,0);
        if(s+PF<192){
            const int s2=s+PF;
            const int zi=s2>>5, n0=((s2>>3)&3)*64, t2=s2&7;
            const short* wz = WTall + (size_t)zi*zWT;
            pb[slot][0] = *(const short8*)(wz + (size_t)(n0+wn+lr)*256 + t2*32 + lq*8);
            pb[slot][1] = *(const short8*)(wz + (size_t)(n0+wn+16+lr)*256 + t2*32 + lq*8);
        }
        if(t==7){
            const int c = s>>3;
            const int zi = c>>2, n0 = (c&3)*64;
            const float* bb = vb + (size_t)zi*256;
            bf16* out = (bf16*)values + (size_t)zi*((size_t)134400*256);
            #pragma unroll
            for(int mi=0;mi<2;mi++){
                #pragma unroll
                for(int rr=0;rr<4;rr++){
                    int gm = m0+wm+mi*16+lq*4+rr;
                    #pragma unroll
                    for(int ni=0;ni<2;ni++){
                        int gn = n0+wn+ni*16+lr;
                        out[(size_t)gm*256+gn] = __float2bfloat16(acc[mi][ni][rr]+bb[gn]);
                    }
                }
            }
        }
    }
}

// ================= fused pos MLP: pos = relu(refd@w1+b1)@w2 + b2 =================
__global__ __launch_bounds__(256) void pos_mlp_kernel(
    const float* __restrict__ refd, const float* __restrict__ w1, const float* __restrict__ b1,
    const short* __restrict__ w2T, const float* __restrict__ b2, float* __restrict__ pos)
{
    __shared__ short hs[32*520];
    __shared__ float rs[32*4];
    int n0 = blockIdx.x*64, m0 = blockIdx.y*32;
    int tid = threadIdx.x;
    if(tid<128) rs[tid] = refd[(size_t)m0*4 + tid];
    __syncthreads();
    {
        int c0 = tid&255;
        float w1r[2][4], b1r[2];
        #pragma unroll
        for(int h=0;h<2;h++){
            int c = c0 + h*256;
            b1r[h] = b1[c];
            #pragma unroll
            for(int k=0;k<4;k++) w1r[h][k] = w1[k*512+c];
        }
        #pragma unroll 4
        for(int j=0;j<64;j++){
            int r = j>>1, h = j&1;
            int c = c0 + h*256;
            float v = 0.f;
            #pragma unroll
            for(int k=0;k<4;k++) v = fmaf(rs[r*4+k], w1r[h][k], v);
            v += b1r[h];
            hs[r*520+c] = f2bf(fmaxf(v,0.f));
        }
    }
    __syncthreads();
    int lane = tid&63, wave = tid>>6;
    int wm = (wave>>1)*16, wn = (wave&1)*32;
    int lr = lane&15, lq = lane>>4;
    float4v acc[2];
    #pragma unroll
    for(int j=0;j<2;j++){ acc[j].x=0.f; acc[j].y=0.f; acc[j].z=0.f; acc[j].w=0.f; }
    short8 pb[2][2];
    #pragma unroll
    for(int ni=0;ni<2;ni++)
        pb[0][ni] = *(const short8*)(w2T + (size_t)(n0+wn+ni*16+lr)*512 + lq*8);
    #pragma unroll
    for(int t=0;t<16;t++){
        const int cur = t&1;
        if(t<15){
            #pragma unroll
            for(int ni=0;ni<2;ni++)
                pb[cur^1][ni] = *(const short8*)(w2T + (size_t)(n0+wn+ni*16+lr)*512 + (t+1)*32 + lq*8);
        }
        short8 a0 = *(const short8*)(&hs[(wm+lr)*520 + t*32 + lq*8]);
        acc[0] = __builtin_amdgcn_mfma_f32_16x16x32_bf16(a0, pb[cur][0], acc[0], 0,0,0);
        acc[1] = __builtin_amdgcn_mfma_f32_16x16x32_bf16(a0, pb[cur][1], acc[1], 0,0,0);
    }
    #pragma unroll
    for(int rr=0;rr<4;rr++){
        int gm = m0+wm+lq*4+rr;
        #pragma unroll
        for(int ni=0;ni<2;ni++){
            int gn = n0+wn+ni*16+lr;
            pos[(size_t)gm*256+gn] = acc[ni][rr] + b2[gn];
        }
    }
}

// ================= MFMA bf16 GEMM (reg-staged double-buffered pipeline) =================
#define LSTR 40

template<int TM, int TN, bool ABF16, bool RELU, bool OUTBF16>
__global__ __launch_bounds__(256) void mfma_gemm_kernel(
    const void* __restrict__ Av, const void* __restrict__ A2v,
    const void* __restrict__ A3v, int nA2lim,
    const short* __restrict__ WT, size_t zWT,
    const float* __restrict__ b0, const float* __restrict__ b1,
    const float* __restrict__ b2, int ns1, int ns2, size_t zB,
    void* __restrict__ Cv, size_t zC, int M, int K, int N, int nxt)
{
    __shared__ short As[2][TM*LSTR];
    __shared__ short Bs[2][TN*LSTR];
    int zz, n0;
    if(nxt){ zz = blockIdx.x / nxt; n0 = (blockIdx.x % nxt)*TN; }
    else   { zz = blockIdx.z;       n0 = blockIdx.x*TN; }
    WT += (size_t)zz*zWT; b0 += (size_t)zz*zB; b1 += (size_t)zz*zB; b2 += (size_t)zz*zB;
    int tid = threadIdx.x;
    int lane = tid&63, wave = tid>>6;
    int m0 = blockIdx.y*TM;
    const int MI = TM/32;
    const int NI = TN/32;
    int wm = (wave>>1)*(TM/2), wn = (wave&1)*(TN/2);
    int lr = lane&15, lq = lane>>4;
    float4v acc[MI][NI];
    #pragma unroll
    for(int i=0;i<MI;i++)
        #pragma unroll
        for(int j=0;j<NI;j++){ acc[i][j].x=0.f; acc[i][j].y=0.f; acc[i][j].z=0.f; acc[i][j].w=0.f; }

    const float* Af; const float* Ad; const short* Ah;
    if(ABF16){ Ah = (const short*)Av; Af=nullptr; Ad=nullptr; }
    else {
        Af = (n0 < nA2lim)? (const float*)Av : (const float*)A3v;
        Ad = (n0 < nA2lim)? (const float*)A2v : nullptr;
        Ah = nullptr;
    }

    short8  rA16[ABF16? TM/64 : 1];
    float4v rAf [ABF16? 1 : TM/32];
    float4v rAd [ABF16? 1 : TM/32];
    short8  rB[TN/64];

    auto LOAD = [&](int k0){
        if constexpr(ABF16){
            #pragma unroll
            for(int it=0; it<TM/64; ++it){
                int idx=(it*256+tid)*8; int r=idx>>5, kk=idx&31; int gm=m0+r;
                short8 v = {};
                if(gm<M) v = *(const short8*)(Ah + (size_t)gm*K + (k0+kk));
                rA16[it]=v;
            }
        } else {
            #pragma unroll
            for(int it=0; it<TM/32; ++it){
                int idx=(it*256+tid)*4; int r=idx>>5, kk=idx&31; int gm=m0+r;
                float4v v; v.x=0.f;v.y=0.f;v.z=0.f;v.w=0.f;
                float4v w; w.x=0.f;w.y=0.f;w.z=0.f;w.w=0.f;
                if(gm<M){
                    v = *(const float4v*)(Af + (size_t)gm*K + (k0+kk));
                    if(Ad) w = *(const float4v*)(Ad + (size_t)gm*K + (k0+kk));
                }
                rAf[it]=v; rAd[it]=w;
            }
        }
        #pragma unroll
        for(int it=0; it<TN/64; ++it){
            int idx=(it*256+tid)*8; int r=idx>>5, kk=idx&31; int gn=n0+r;
            short8 v = {};
            if(gn<N) v = *(const short8*)(WT + (size_t)gn*K + (k0+kk));
            rB[it]=v;
        }
    };
    auto STORE = [&](int buf){
        if constexpr(ABF16){
            #pragma unroll
            for(int it=0; it<TM/64; ++it){
                int idx=(it*256+tid)*8; int r=idx>>5, kk=idx&31;
                *(short8*)(&As[buf][r*LSTR+kk]) = rA16[it];
            }
        } else {
            #pragma unroll
            for(int it=0; it<TM/32; ++it){
                int idx=(it*256+tid)*4; int r=idx>>5, kk=idx&31;
                float4v v = rAf[it];
                if(Ad){ v.x+=rAd[it].x; v.y+=rAd[it].y; v.z+=rAd[it].z; v.w+=rAd[it].w; }
                short4v h; h.x=f2bf(v.x); h.y=f2bf(v.y); h.z=f2bf(v.z); h.w=f2bf(v.w);
                *(short4v*)(&As[buf][r*LSTR+kk]) = h;
            }
        }
        #pragma unroll
        for(int it=0; it<TN/64; ++it){
            int idx=(it*256+tid)*8; int r=idx>>5, kk=idx&31;
            *(short8*)(&Bs[buf][r*LSTR+kk]) = rB[it];
        }
    };

    const int nt = K>>5;
    LOAD(0);
    STORE(0);
    __syncthreads();
    for(int t=0; t<nt; ++t){
        int cb = t&1;
        if(t+1<nt) LOAD((t+1)<<5);
        short8 af[MI], bfr[NI];
        #pragma unroll
        for(int mi=0;mi<MI;mi++) af[mi]  = *(const short8*)(&As[cb][(wm+mi*16+lr)*LSTR + lq*8]);
        #pragma unroll
        for(int ni=0;ni<NI;ni++) bfr[ni] = *(const short8*)(&Bs[cb][(wn+ni*16+lr)*LSTR + lq*8]);
        #pragma unroll
        for(int mi=0;mi<MI;mi++)
            #pragma unroll
            for(int ni=0;ni<NI;ni++)
                acc[mi][ni] = __builtin_amdgcn_mfma_f32_16x16x32_bf16(af[mi], bfr[ni], acc[mi][ni], 0,0,0);
        if(t+1<nt){
            STORE(cb^1);
            __syncthreads();
        }
    }
    float* Cf=(float*)Cv + (size_t)zz*zC; bf16* Ch=(bf16*)Cv + (size_t)zz*zC;
    #pragma unroll
    for(int mi=0;mi<MI;mi++){
        #pragma unroll
        for(int r=0;r<4;r++){
            int gm = m0+wm+mi*16+lq*4+r;
            if(gm>=M) continue;
            #pragma unroll
            for(int ni=0;ni<NI;ni++){
                int gn = n0+wn+ni*16+lr;
                if(gn>=N) continue;
                float bv = (gn<ns1)? b0[gn] : ((gn<ns2)? b1[gn-ns1] : b2[gn-ns2]);
                float v = acc[mi][ni][r] + bv;
                if(RELU) v = fmaxf(v,0.f);
                if(OUTBF16) Ch[(size_t)gm*N+gn]=__float2bfloat16(v);
                else        Cf[(size_t)gm*N+gn]=v;
            }
        }
    }
}

// ================= fused MHA (union LDS, vectorized staging, bf16 out) =================
__global__ __launch_bounds__(256) void fused_mha_kernel(
    const float* __restrict__ QKV, short* __restrict__ O)
{
    const int ld = 768;
    int bh = blockIdx.y; int b = bh>>3, h = bh&7;
    int q0 = blockIdx.x*64;
    __shared__ short lds[31104];   // 62208 B
    short* Vts = lds;              // 32 x 324
    short* Qs  = lds + 10368;      // 64 x 36
    short* Ks  = lds + 12672;      // 304 x 36
    short* Ps  = lds + 10368;      // 64 x 324, overlays Qs+Ks after S-phase
    int tid = threadIdx.x;
    for(int idx=tid; idx<64*8; idx+=256){
        int r=idx>>3, c4=(idx&7)*4; int gq=q0+r;
        float4v v; v.x=0.f;v.y=0.f;v.z=0.f;v.w=0.f;
        if(gq<NQ_) v = *(const float4v*)(QKV + ((size_t)(b*NQ_+gq))*ld + h*DH_ + c4);
        short4v h4; h4.x=f2bf(v.x);h4.y=f2bf(v.y);h4.z=f2bf(v.z);h4.w=f2bf(v.w);
        *(short4v*)(Qs + r*36 + c4) = h4;
    }
    for(int idx=tid; idx<304*8; idx+=256){
        int r=idx>>3, c4=(idx&7)*4;
        float4v v; v.x=0.f;v.y=0.f;v.z=0.f;v.w=0.f;
        if(r<NQ_) v = *(const float4v*)(QKV + 256 + ((size_t)(b*NQ_+r))*ld + h*DH_ + c4);
        short4v h4; h4.x=f2bf(v.x);h4.y=f2bf(v.y);h4.z=f2bf(v.z);h4.w=f2bf(v.w);
        *(short4v*)(Ks + r*36 + c4) = h4;
    }
    for(int idx=tid; idx<320*8; idx+=256){
        int r=idx>>3, c4=(idx&7)*4;
        float4v v; v.x=0.f;v.y=0.f;v.z=0.f;v.w=0.f;
        if(r<NQ_) v = *(const float4v*)(QKV + 512 + ((size_t)(b*NQ_+r))*ld + h*DH_ + c4);
        Vts[(c4+0)*324+r]=f2bf(v.x); Vts[(c4+1)*324+r]=f2bf(v.y);
        Vts[(c4+2)*324+r]=f2bf(v.z); Vts[(c4+3)*324+r]=f2bf(v.w);
    }
    __syncthreads();

    int lane = tid&63, wave = tid>>6;
    int lr = lane&15, lq = lane>>4;
    int mrow = wave*16;
    const float scale = 0.17677669529663687f;

    float4v acc[19];
    #pragma unroll
    for(int t=0;t<19;t++){ acc[t].x=0.f; acc[t].y=0.f; acc[t].z=0.f; acc[t].w=0.f; }
    short8 afrag = *(const short8*)(&Qs[(mrow+lr)*36 + lq*8]);
    #pragma unroll
    for(int t=0;t<19;t++){
        short8 bfrag = *(const short8*)(&Ks[(t*16+lr)*36 + lq*8]);
        acc[t] = __builtin_amdgcn_mfma_f32_16x16x32_bf16(afrag, bfrag, acc[t], 0,0,0);
    }
    __syncthreads();   // Qs/Ks dead; Ps overlay becomes writable

    for(int idx=tid; idx<64*16; idx+=256){
        int r=idx>>4, c=idx&15;
        Ps[r*324 + 304 + c]=0;
    }
    #pragma unroll
    for(int t=0;t<19;t++){
        #pragma unroll
        for(int r=0;r<4;r++) acc[t][r] *= scale;
    }
    if(lr>=12){
        #pragma unroll
        for(int r=0;r<4;r++) acc[18][r] = -1e30f;
    }
    float mx[4];
    #pragma unroll
    for(int r=0;r<4;r++){
        float m = acc[0][r];
        #pragma unroll
        for(int t=1;t<19;t++) m = fmaxf(m, acc[t][r]);
        m = fmaxf(m, __shfl_xor(m,1)); m = fmaxf(m, __shfl_xor(m,2));
        m = fmaxf(m, __shfl_xor(m,4)); m = fmaxf(m, __shfl_xor(m,8));
        mx[r]=m;
    }
    float sum[4] = {0.f,0.f,0.f,0.f};
    #pragma unroll
    for(int t=0;t<19;t++){
        #pragma unroll
        for(int r=0;r<4;r++){
            float p = __expf(acc[t][r]-mx[r]);
            acc[t][r]=p; sum[r]+=p;
        }
    }
    #pragma unroll
    for(int r=0;r<4;r++){
        float s = sum[r];
        s += __shfl_xor(s,1); s += __shfl_xor(s,2);
        s += __shfl_xor(s,4); s += __shfl_xor(s,8);
        sum[r] = 1.f/s;
    }
    #pragma unroll
    for(int t=0;t<19;t++){
        #pragma unroll
        for(int r=0;r<4;r++){
            Ps[(mrow + lq*4 + r)*324 + t*16 + lr] = f2bf(acc[t][r]*sum[r]);
        }
    }
    __syncthreads();
    float4v oacc[2];
    oacc[0].x=0.f;oacc[0].y=0.f;oacc[0].z=0.f;oacc[0].w=0.f;
    oacc[1]=oacc[0];
    #pragma unroll
    for(int kc=0;kc<10;kc++){
        short8 pa = *(const short8*)(&Ps[(mrow+lr)*324 + kc*32 + lq*8]);
        #pragma unroll
        for(int n=0;n<2;n++){
            short8 vb = *(const short8*)(&Vts[(n*16+lr)*324 + kc*32 + lq*8]);
            oacc[n] = __builtin_amdgcn_mfma_f32_16x16x32_bf16(pa, vb, oacc[n], 0,0,0);
        }
    }
    #pragma unroll
    for(int n=0;n<2;n++){
        #pragma unroll
        for(int r=0;r<4;r++){
            int gq = q0 + mrow + lq*4 + r;
            if(gq<NQ_)
                O[((size_t)(b*NQ_+gq))*D_ + h*DH_ + n*16 + lr] = f2bf(oacc[n][r]);
        }
    }
}

// ============== all-weights transpose f32[K][N] -> bf16[N][K] ==============
#define NTD 74
struct TD { const float* src; unsigned dstoff; int K, N, base; };
struct TAll { TD d[NTD]; };

__global__ __launch_bounds__(256) void transpose_all_kernel(TAll p, short* __restrict__ WTb){
    int blk = blockIdx.x;
    int di = 0;
    #pragma unroll 1
    for(int i=0;i<NTD;i++){ if(blk >= p.d[i].base) di = i; }
    TD d = p.d[di];
    int rel = blk - d.base;
    int ntx = (d.N+31)/32;
    int tn = (rel % ntx)*32, tk = (rel / ntx)*32;
    __shared__ float t[32][33];
    int tx = threadIdx.x&31, ty = threadIdx.x>>5;
    for(int i=0;i<32;i+=8){
        int k = tk+ty+i, n = tn+tx;
        t[ty+i][tx] = (k<d.K && n<d.N)? d.src[(size_t)k*d.N+n] : 0.f;
    }
    __syncthreads();
    short* out = WTb + d.dstoff;
    for(int i=0;i<32;i+=8){
        int n = tn+ty+i, k = tk+tx;
        if(n<d.N && k<d.K) out[(size_t)n*d.K+k] = f2bf(t[tx][ty+i]);
    }
}

// ================= SIMT GEMM (tiny K/N; optional fused bbox-update epilogue) =================
template<bool RELU, bool BBOX>
__global__ __launch_bounds__(256) void gemm_kernel(
    const float* __restrict__ A, const float* __restrict__ W,
    const float* __restrict__ bias, float* __restrict__ Cf,
    int M, int K, int N)
{
    __shared__ float As[16][68];
    __shared__ float Bs[16][68];
    int tid = threadIdx.x;
    int m0 = blockIdx.y*64, n0 = blockIdx.x*64;
    int tm = tid>>4, tn = tid&15;
    float acc[4][4] = {};
    int lam = tid>>2;
    int lak = (tid&3)*4;
    int lbk = tid>>4;
    int lbn = (tid&15)*4;
    for(int k0=0;k0<K;k0+=16){
        {
            int m = m0+lam;
            #pragma unroll
            for(int j=0;j<4;j++){
                int k = k0+lak+j;
                float v=0.f;
                if(m<M && k<K) v = A[(size_t)m*K+k];
                As[lak+j][lam]=v;
            }
        }
        {
            int k = k0+lbk;
            #pragma unroll
            for(int j=0;j<4;j++){
                int n = n0+lbn+j;
                float v=0.f;
                if(k<K && n<N) v = W[(size_t)k*N+n];
                Bs[lbk][lbn+j]=v;
            }
        }
        __syncthreads();
        #pragma unroll
        for(int kk=0;kk<16;kk++){
            float a[4], bb[4];
            #pragma unroll
            for(int i=0;i<4;i++) a[i]=As[kk][tm*4+i];
            #pragma unroll
            for(int j=0;j<4;j++) bb[j]=Bs[kk][tn*4+j];
            #pragma unroll
            for(int i=0;i<4;i++)
                #pragma unroll
                for(int j=0;j<4;j++) acc[i][j] += a[i]*bb[j];
        }
        __syncthreads();
    }
    #pragma unroll
    for(int i=0;i<4;i++){
        int m=m0+tm*4+i; if(m>=M) continue;
        #pragma unroll
        for(int j=0;j<4;j++){
            int n=n0+tn*4+j; if(n>=N) continue;
            float v = acc[i][j] + bias[n];
            if(BBOX){
                float x = Cf[(size_t)m*N+n];
                x = fminf(fmaxf(x,0.f),1.f);
                float num = fmaxf(x,1e-5f), den = fmaxf(1.f-x,1e-5f);
                float nd = v + logf(num/den);
                Cf[(size_t)m*N+n] = 1.f/(1.f+expf(-nd));
            } else {
                if(RELU) v = fmaxf(v,0.f);
                Cf[(size_t)m*N+n]=v;
            }
        }
    }
}

// ---------------- small elementwise kernels ----------------
__global__ void copy_kernel(const float* __restrict__ a, float* __restrict__ o, int n){
    int i = blockIdx.x*blockDim.x+threadIdx.x;
    if(i<n) o[i]=a[i];
}
__global__ void cvt_f32_bf16_kernel(const float* __restrict__ a, short* __restrict__ o, int n4){
    int i = blockIdx.x*blockDim.x+threadIdx.x;
    if(i<n4){
        float4v v = *(const float4v*)(a + (size_t)i*4);
        short4v h; h.x=f2bf(v.x); h.y=f2bf(v.y); h.z=f2bf(v.z); h.w=f2bf(v.w);
        *(short4v*)(o + (size_t)i*4) = h;
    }
}
__global__ void sigmoid_init_kernel(const float* __restrict__ a, float* __restrict__ o, int n){
    int i = blockIdx.x*blockDim.x+threadIdx.x;
    if(i<n){ float x=a[i]; o[i]=1.f/(1.f+expf(-x)); }
}
__global__ void write_out_kernel(const float* __restrict__ refd, const float* __restrict__ logits, float* __restrict__ out){
    int i = blockIdx.x*blockDim.x+threadIdx.x;
    if(i<BN_*4) out[i]=refd[i];
    else if(i<BN_*4+BN_*NCLS_) out[i]=logits[i-BN_*4];
}

// ---------------- layernorm with residual (t2 bf16), optional bf16 copy-out ----------------
__global__ __launch_bounds__(256) void ln_residual_kernel(
    float* __restrict__ cur, const short* __restrict__ t2b,
    const float* __restrict__ g, const float* __restrict__ b,
    short* __restrict__ cb)
{
    int row = blockIdx.x; int c = threadIdx.x;
    size_t idx = (size_t)row*D_+c;
    float x = cur[idx] + bf2f(t2b[idx]);
    float v1 = x, v2 = x*x;
    #pragma unroll
    for(int o=32;o>0;o>>=1){ v1 += __shfl_down(v1,o,64); v2 += __shfl_down(v2,o,64); }
    __shared__ float s1[4], s2[4], st[2];
    int wid=c>>6, lane=c&63;
    if(lane==0){ s1[wid]=v1; s2[wid]=v2; }
    __syncthreads();
    if(c==0){
        float a=0,d=0;
        #pragma unroll
        for(int i=0;i<4;i++){a+=s1[i]; d+=s2[i];}
        st[0]=a/(float)D_; st[1]=d/(float)D_;
    }
    __syncthreads();
    float m=st[0], var=st[1]-m*m;
    float y = (x-m)*rsqrtf(var+1e-5f)*g[c] + b[c];
    cur[idx]=y;
    if(cb) cb[idx]=f2bf(y);
}

// ---------------- deformable sampling (fused attw softmax, bf16 out) ----------------
__global__ __launch_bounds__(256) void deform_sample_kernel(
    const float* __restrict__ refd, const float* __restrict__ oab,
    const bf16* __restrict__ value, short* __restrict__ outacc)
{
    int row = blockIdx.x; int b = row/NQ_;
    int tid = threadIdx.x; int h = tid>>5, c = tid&31;
    __shared__ float so[192], sa[96], sr[4];
    if(tid<192) so[tid]=oab[(size_t)row*288+tid];
    if(tid<96)  sa[tid]=oab[(size_t)row*288+192+tid];
    if(tid<4)   sr[tid]=refd[(size_t)row*4+tid];
    __syncthreads();
    if(tid<8){
        float* p = sa + tid*12;
        float m=-1e30f;
        #pragma unroll
        for(int i2=0;i2<12;i2++) m=fmaxf(m,p[i2]);
        float s=0.f;
        #pragma unroll
        for(int i2=0;i2<12;i2++){ float e=__expf(p[i2]-m); p[i2]=e; s+=e; }
        float inv=1.f/s;
        #pragma unroll
        for(int i2=0;i2<12;i2++) p[i2]*=inv;
    }
    __syncthreads();
    float cx=sr[0], cy=sr[1], rw=sr[2], rh=sr[3];
    const int HS[3]={80,40,20}, WS[3]={80,40,20}, ST[3]={0,6400,8000};
    float acc=0.f;
    const bf16* vb = value + (size_t)b*LM_*D_ + h*DH_ + c;
    for(int lv=0;lv<3;lv++){
        int Hl=HS[lv], Wl=WS[lv], st=ST[lv];
        #pragma unroll
        for(int pt=0;pt<4;pt++){
            int oi = ((h*3+lv)*4+pt)*2;
            float ox=so[oi], oy=so[oi+1];
            float wa=sa[h*12+lv*4+pt];
            float lx = cx + ox*0.25f*rw*0.5f;
            float ly = cy + oy*0.25f*rh*0.5f;
            float x = lx*(float)Wl - 0.5f, y = ly*(float)Hl - 0.5f;
            float x0f=floorf(x), y0f=floorf(y);
            float wx=x-x0f, wy=y-y0f;
            int x0=(int)x0f, y0=(int)y0f;
            #pragma unroll
            for(int dy=0;dy<2;dy++){
                #pragma unroll
                for(int dx=0;dx<2;dx++){
                    int xi=x0+dx, yi=y0+dy;
                    if(xi>=0 && xi<Wl && yi>=0 && yi<Hl){
                        float w = (dx? wx : 1.f-wx)*(dy? wy : 1.f-wy);
                        int lin = yi*Wl+xi;
                        acc += __bfloat162float(vb[(size_t)(st+lin)*D_]) * (w*wa);
                    }
                }
            }
        }
    }
    outacc[(size_t)row*D_+tid]=f2bf(acc);
}

// ---------------- host helpers ----------------
static void gemm_bbox(const float*A, const float*W, const float*b, float*refd,
                      int M,int K,int N, hipStream_t s){
    dim3 g((N+63)/64,(M+63)/64);
    gemm_kernel<false,true><<<g,256,0,s>>>(A,W,b,refd,M,K,N);
}
// tail GEMM dispatcher: TM=64, TN=64
static void g64x(const void*A, const void*A2, const void*A3, int nA2lim,
                 const short*WT, const float*b0, const float*b1, const float*b2,
                 int ns1, int ns2, void*C, int M,int K,int N,
                 bool abf16, bool relu, bool outbf, hipStream_t s){
    dim3 g((N+63)/64,(M+63)/64,1);
    #define CALLG(AB,RL,OB) mfma_gemm_kernel<64,64,AB,RL,OB><<<g,256,0,s>>>(A,A2,A3,nA2lim,WT,0,b0,b1,b2,ns1,ns2,0,C,0,M,K,N,0)
    if(abf16){
        if(relu){ if(outbf) CALLG(true,true,true);  else CALLG(true,true,false); }
        else    { if(outbf) CALLG(true,false,true); else CALLG(true,false,false); }
    } else {
        if(relu){ if(outbf) CALLG(false,true,true);  else CALLG(false,true,false); }
        else    { if(outbf) CALLG(false,false,true); else CALLG(false,false,false); }
    }
    #undef CALLG
}
static void g64(const float*A, const float*A2, const float*A3, int nA2lim,
                const short*WT, const float*b0, const float*b1, const float*b2,
                int ns1, int ns2, void*C, int M,int K,int N,
                bool relu, bool outbf, hipStream_t s){
    g64x(A,A2,A3,nA2lim,WT,b0,b1,b2,ns1,ns2,C,M,K,N,false,relu,outbf,s);
}
static void g64b(const short*A, const short*WT, const float*b, void*C,
                 int M,int K,int N, hipStream_t s){
    g64x(A,nullptr,nullptr,1<<30,WT,b,b,b,N,N+1,C,M,K,N,true,false,true,s);
}
static int ntiles(int K,int N){ return ((N+31)/32)*((K+31)/32); }

extern "C" void kernel_launch(void* const* d_in, const int* in_sizes, int n_in,
                              void* d_out, int out_size, void* d_ws, size_t ws_size,
                              hipStream_t stream) {
    const float* tgt   = (const float*)d_in[0];
    const float* rpu   = (const float*)d_in[1];
    const float* mem   = (const float*)d_in[2];
    const float* sa_wq = (const float*)d_in[3];
    const float* sa_wk = (const float*)d_in[4];
    const float* sa_wv = (const float*)d_in[5];
    const float* sa_wo = (const float*)d_in[6];
    const float* val_w = (const float*)d_in[7];
    const float* out_w = (const float*)d_in[8];
    const float* bb_w1 = (const float*)d_in[9];
    const float* bb_w2 = (const float*)d_in[10];
    const float* sa_bq = (const float*)d_in[11];
    const float* sa_bk = (const float*)d_in[12];
    const float* sa_bv = (const float*)d_in[13];
    const float* sa_bo = (const float*)d_in[14];
    const float* ln1_b = (const float*)d_in[15];
    const float* ln2_b = (const float*)d_in[16];
    const float* ln3_b = (const float*)d_in[17];
    const float* val_b = (const float*)d_in[18];
    const float* out_b = (const float*)d_in[19];
    const float* ffn_b2= (const float*)d_in[20];
    const float* bb_b1 = (const float*)d_in[21];
    const float* bb_b2 = (const float*)d_in[22];
    const float* ln1_g = (const float*)d_in[23];
    const float* ln2_g = (const float*)d_in[24];
    const float* ln3_g = (const float*)d_in[25];
    const float* off_w = (const float*)d_in[26];
    const float* off_b = (const float*)d_in[27];
    const float* attw_w= (const float*)d_in[28];
    const float* attw_b= (const float*)d_in[29];
    const float* ffn_w1= (const float*)d_in[30];
    const float* ffn_b1= (const float*)d_in[31];
    const float* ffn_w2= (const float*)d_in[32];
    const float* bb_w3 = (const float*)d_in[33];
    const float* bb_b3 = (const float*)d_in[34];
    const float* sc_w  = (const float*)d_in[35];
    const float* sc_b  = (const float*)d_in[36];
    const float* qp_w1 = (const float*)d_in[37];
    const float* qp_b1 = (const float*)d_in[38];
    const float* qp_w2 = (const float*)d_in[39];
    const float* qp_b2 = (const float*)d_in[40];

    const size_t BND = (size_t)BN_*D_;          // 1,228,800
    const size_t USZ = (size_t)BN_*DFF_;        // 4,915,200 floats (union)
    const size_t LMD = (size_t)BS_*LM_*D_;      // 34,406,400
    const size_t LSZ = 1122304;                 // WT shorts per layer

    float* ws   = (float*)d_ws;
    float* cur  = ws;
    float* pos  = cur + BND;
    float* refd = pos + BND;
    float* U    = refd + (size_t)BN_*4;
    short* tmp16 = (short*)(U + USZ);
    short* t216  = tmp16 + BND;
    short* WT    = t216 + BND;
    short* qp2T  = WT + 6*LSZ;
    short* scT   = qp2T + 131072;
    short* X     = scT + 20480;
    // U aliases (phase-disjoint)
    float* QKVh   = U;
    float* offsb  = U;
    short* ffnh16 = (short*)U;
    short* bb1b   = (short*)U;
    float* bb2    = U + BND;
    float* logitsb= U;
    short* curb = tmp16;

    size_t offX = (size_t)((char*)X - (char*)d_ws);
    int vmode;
    if(ws_size >= offX + 7*LMD*2)      vmode = 3;
    else if(ws_size >= offX + 6*LMD*2) vmode = 2;
    else if(ws_size >= offX + 4*LMD)   vmode = 1;
    else                               vmode = 0;
    short* memT   = X;
    short* values = (vmode==3)? X + LMD : X;
    short* value1 = X + LMD;
    short* value0 = X;

    const int nBN_D = (int)BND;
    copy_kernel<<<(nBN_D+255)/256,256,0,stream>>>(tgt, cur, nBN_D);
    sigmoid_init_kernel<<<(BN_*4+255)/256,256,0,stream>>>(rpu, refd, BN_*4);
    if(vmode==1 || vmode==3){
        int n4 = (int)(LMD/4);
        cvt_f32_bf16_kernel<<<(n4+255)/256,256,0,stream>>>(mem, memT, n4);
    }

    // ---- transpose ALL weights upfront (one launch) ----
    {
        TAll tp; int base=0; int di=0;
        const size_t offs[12] = { 0,65536,131072,196608,262144,327680,
                                  393216,442368,466944,729088,991232,1056768 };
        const int Ks[12] = { 256,256,256,256,256,256,256,256,256,1024,256,256 };
        const int Ns[12] = { 256,256,256,256,256,256,192,96,1024,256,256,256 };
        for(int l=0;l<NLAYERS_;l++){
            const float* srcs[12] = { sa_wq+(size_t)l*D_*D_, sa_wk+(size_t)l*D_*D_, sa_wv+(size_t)l*D_*D_,
                                      sa_wo+(size_t)l*D_*D_, val_w+(size_t)l*D_*D_, out_w+(size_t)l*D_*D_,
                                      off_w+(size_t)l*D_*192, attw_w+(size_t)l*D_*96,
                                      ffn_w1+(size_t)l*D_*DFF_, ffn_w2+(size_t)l*DFF_*D_,
                                      bb_w1+(size_t)l*D_*D_, bb_w2+(size_t)l*D_*D_ };
            for(int j=0;j<12;j++){
                tp.d[di] = { srcs[j], (unsigned)(l*LSZ + offs[j]), Ks[j], Ns[j], base };
                base += ntiles(Ks[j],Ns[j]); di++;
            }
        }
        tp.d[di] = { qp_w2, (unsigned)(6*LSZ), 512, 256, base }; base += ntiles(512,256); di++;
        tp.d[di] = { sc_w + (size_t)(NLAYERS_-1)*D_*NCLS_, (unsigned)(6*LSZ+131072), 256, 80, base }; base += ntiles(256,80); di++;
        transpose_all_kernel<<<base,256,0,stream>>>(tp, WT);
    }

    // ---- value projections ----
    if(vmode==3){
        valproj_kernel<<<2100,256,0,stream>>>(memT, WT+262144, LSZ, val_b, values);
    } else if(vmode==2){
        dim3 g(12,1050,1);
        mfma_gemm_kernel<128,128,false,false,true><<<g,256,0,stream>>>(
            mem,nullptr,mem,1<<30, WT+262144, LSZ,
            val_b,val_b,val_b, 256,257, 256, values, LMD, BS_*LM_, D_, D_, 2);
    }

    for(int i=0;i<NLAYERS_;i++){
        const bf16* value_i;
        if(vmode>=2) value_i = (const bf16*)(values + (size_t)i*LMD);
        else {
            dim3 g(2,1050,1);
            if(vmode==1){
                mfma_gemm_kernel<128,128,true,false,true><<<g,256,0,stream>>>(
                    memT,nullptr,nullptr,1<<30, WT+i*LSZ+262144, 0,
                    val_b+(size_t)i*D_,val_b,val_b, 256,257, 0, value1, 0, BS_*LM_, D_, D_, 0);
                value_i = (const bf16*)value1;
            } else {
                mfma_gemm_kernel<128,128,false,false,true><<<g,256,0,stream>>>(
                    mem,nullptr,mem,1<<30, WT+i*LSZ+262144, 0,
                    val_b+(size_t)i*D_,val_b,val_b, 256,257, 0, value0, 0, BS_*LM_, D_, D_, 0);
                value_i = (const bf16*)value0;
            }
        }
        // pos = MLP2(refd) — fused single kernel
        pos_mlp_kernel<<<dim3(4,150),256,0,stream>>>(refd, qp_w1, qp_b1, qp2T, qp_b2, pos);
        // QKV fused: Q,K from cur+pos (n<512), V from cur
        g64(cur, pos, cur, 512, WT+i*LSZ,
            sa_bq+(size_t)i*D_, sa_bk+(size_t)i*D_, sa_bv+(size_t)i*D_, 256, 512,
            QKVh, BN_, D_, 768, false,false, stream);
        {
            dim3 g((NQ_+63)/64, BS_*NHEAD_);
            fused_mha_kernel<<<g,256,0,stream>>>(QKVh, tmp16);
        }
        g64b(tmp16, WT+i*LSZ+196608, sa_bo+(size_t)i*D_, t216, BN_, D_, D_, stream);
        ln_residual_kernel<<<BN_,256,0,stream>>>(cur, t216, ln1_g+(size_t)i*D_, ln1_b+(size_t)i*D_, nullptr);
        // deformable attention: fused off|attw projection from cur+pos
        g64(cur, pos, cur, 1<<30, WT+i*LSZ+393216,
            off_b+(size_t)i*192, attw_b+(size_t)i*96, attw_b+(size_t)i*96, 192, 288,
            offsb, BN_, D_, 288, false,false, stream);
        deform_sample_kernel<<<BN_,256,0,stream>>>(refd, offsb, value_i, tmp16);
        g64b(tmp16, WT+i*LSZ+327680, out_b+(size_t)i*D_, t216, BN_, D_, D_, stream);
        ln_residual_kernel<<<BN_,256,0,stream>>>(cur, t216, ln2_g+(size_t)i*D_, ln2_b+(size_t)i*D_, curb);
        // FFN: A = bf16 cur (from ln2), hidden bf16, FFN2 bf16-A
        g64x(curb,nullptr,nullptr,1<<30, WT+i*LSZ+466944, ffn_b1+(size_t)i*DFF_,ffn_b1,ffn_b1, DFF_,DFF_+1,
             ffnh16, BN_, D_, DFF_, true,true,true, stream);
        g64x(ffnh16,nullptr,nullptr,1<<30, WT+i*LSZ+729088, ffn_b2+(size_t)i*D_,ffn_b2,ffn_b2, 256,257,
             t216, BN_, DFF_, D_, true,false,true, stream);
        ln_residual_kernel<<<BN_,256,0,stream>>>(cur, t216, ln3_g+(size_t)i*D_, ln3_b+(size_t)i*D_, curb);
        // bbox head: bf16-A chain, bb3+bbox_update fused
        g64x(curb,nullptr,nullptr,1<<30, WT+i*LSZ+991232, bb_b1+(size_t)i*D_,bb_b1,bb_b1, 256,257,
             bb1b, BN_, D_, D_, true,true,true, stream);
        g64x(bb1b,nullptr,nullptr,1<<30, WT+i*LSZ+1056768, bb_b2+(size_t)i*D_,bb_b2,bb_b2, 256,257,
             bb2, BN_, D_, D_, true,true,false, stream);
        gemm_bbox(bb2, bb_w3+(size_t)i*D_*4, bb_b3+(size_t)i*4, refd, BN_, D_, 4, stream);
    }
    // final score GEMM: A = bf16 cur (curb from layer-5 ln3)
    g64x(curb,nullptr,nullptr,1<<30, scT, sc_b+(size_t)(NLAYERS_-1)*NCLS_,sc_b,sc_b, NCLS_,NCLS_+1,
         logitsb, BN_, D_, NCLS_, true,false,false, stream);
    int tot = BN_*4 + BN_*NCLS_;
    write_out_kernel<<<(tot+255)/256,256,0,stream>>>(refd, logitsb, (float*)d_out);
}

// Round 8
// 2166.998 us; speedup vs baseline: 1.1205x; 1.1192x over previous
//
#include <hip/hip_runtime.h>
#include <hip/hip_bf16.h>

typedef __hip_bfloat16 bf16;
typedef short short8 __attribute__((ext_vector_type(8)));
typedef short short4v __attribute__((ext_vector_type(4)));
typedef float float4v __attribute__((ext_vector_type(4)));

#define D_ 256
#define NHEAD_ 8
#define DH_ 32
#define NQ_ 300
#define NLAYERS_ 6
#define DFF_ 1024
#define NCLS_ 80
#define BS_ 16
#define LM_ 8400
#define BN_ (BS_*NQ_)   // 4800

static __device__ __forceinline__ short f2bf(float x){
    union{float f; unsigned u;} v; v.f = x;
    unsigned r = v.u + 0x7FFF + ((v.u>>16)&1);
    return (short)(r>>16);
}
static __device__ __forceinline__ float bf2f(short s){
    union{unsigned u; float f;} v; v.u = ((unsigned)(unsigned short)s)<<16; return v.f;
}

// ================= fused bbox head: refd = sigmoid(mlp3(curb) + inv_sig(refd)) =================
// Replaces bb1 GEMM + bb2 GEMM + bb3 SIMT + bbox_update (3 launches + 2 ws round-trips).
// 16 rows/block (grid 300). h1 bf16 LDS (same rounding as old bb1b store); h2 f32 LDS
// (bit-identical to old bb2 output); phase3 = SIMT N=4 with 4-way k-quarter shfl reduce.
__global__ __launch_bounds__(256) void bbox_head_kernel(
    const short* __restrict__ curb,
    const short* __restrict__ w1T, const float* __restrict__ b1,
    const short* __restrict__ w2T, const float* __restrict__ b2,
    const float* __restrict__ w3, const float* __restrict__ b3,
    float* __restrict__ refd)
{
    __shared__ short h1[16*264];
    __shared__ float h2[16*260];
    int m0 = blockIdx.x*16;
    int tid = threadIdx.x, lane = tid&63, wave = tid>>6;
    int lr = lane&15, lq = lane>>4;
    int n0 = wave*64;
    // A fragments: rows m0+lr, full K=256
    short8 af[8];
    #pragma unroll
    for(int kt=0;kt<8;kt++)
        af[kt] = *(const short8*)(curb + (size_t)(m0+lr)*256 + kt*32 + lq*8);
    // ---- phase 1: h1 = relu(curb @ w1T + b1), bf16 to LDS ----
    float4v acc[4];
    #pragma unroll
    for(int nf=0;nf<4;nf++){ acc[nf].x=0.f; acc[nf].y=0.f; acc[nf].z=0.f; acc[nf].w=0.f; }
    #pragma unroll
    for(int kt=0;kt<8;kt++){
        #pragma unroll
        for(int nf=0;nf<4;nf++){
            short8 bfr = *(const short8*)(w1T + (size_t)(n0+nf*16+lr)*256 + kt*32 + lq*8);
            acc[nf] = __builtin_amdgcn_mfma_f32_16x16x32_bf16(af[kt], bfr, acc[nf], 0,0,0);
        }
    }
    #pragma unroll
    for(int nf=0;nf<4;nf++){
        #pragma unroll
        for(int rr=0;rr<4;rr++){
            int row = lq*4+rr, gn = n0+nf*16+lr;
            float v = acc[nf][rr] + b1[gn];
            v = fmaxf(v,0.f);
            ((bf16*)h1)[row*264+gn] = __float2bfloat16(v);
        }
    }
    __syncthreads();
    // ---- phase 2: h2 = relu(h1 @ w2T + b2), f32 to LDS ----
    #pragma unroll
    for(int nf=0;nf<4;nf++){ acc[nf].x=0.f; acc[nf].y=0.f; acc[nf].z=0.f; acc[nf].w=0.f; }
    #pragma unroll
    for(int kt=0;kt<8;kt++){
        short8 a2 = *(const short8*)(&h1[lr*264 + kt*32 + lq*8]);
        #pragma unroll
        for(int nf=0;nf<4;nf++){
            short8 bfr = *(const short8*)(w2T + (size_t)(n0+nf*16+lr)*256 + kt*32 + lq*8);
            acc[nf] = __builtin_amdgcn_mfma_f32_16x16x32_bf16(a2, bfr, acc[nf], 0,0,0);
        }
    }
    #pragma unroll
    for(int nf=0;nf<4;nf++){
        #pragma unroll
        for(int rr=0;rr<4;rr++){
            int row = lq*4+rr, gn = n0+nf*16+lr;
            float v = acc[nf][rr] + b2[gn];
            h2[row*260+gn] = fmaxf(v,0.f);
        }
    }
    __syncthreads();
    // ---- phase 3: delta = h2 @ w3 + b3; refd = sigmoid(delta + inv_sig(clamp(refd))) ----
    {
        int row = tid>>4, sub = tid&15;
        int n = sub>>2, kq = sub&3;
        float p = 0.f;
        const float* hr = h2 + row*260 + kq*64;
        #pragma unroll
        for(int k=0;k<64;k++) p = fmaf(hr[k], w3[(kq*64+k)*4+n], p);
        p += __shfl_xor(p,1);
        p += __shfl_xor(p,2);
        if(kq==0){
            float delta = p + b3[n];
            size_t idx = (size_t)(m0+row)*4+n;
            float x = refd[idx];
            x = fminf(fmaxf(x,0.f),1.f);
            float num = fmaxf(x,1e-5f), den = fmaxf(1.f-x,1e-5f);
            float nd = delta + logf(num/den);
            refd[idx] = 1.f/(1.f+expf(-nd));
        }
    }
}

// ================= fused pos MLP: pos = relu(refd@w1+b1)@w2 + b2 =================
__global__ __launch_bounds__(256) void pos_mlp_kernel(
    const float* __restrict__ refd, const float* __restrict__ w1, const float* __restrict__ b1,
    const short* __restrict__ w2T, const float* __restrict__ b2, float* __restrict__ pos)
{
    __shared__ short hs[32*520];
    __shared__ float rs[32*4];
    int n0 = blockIdx.x*64, m0 = blockIdx.y*32;
    int tid = threadIdx.x;
    if(tid<128) rs[tid] = refd[(size_t)m0*4 + tid];
    __syncthreads();
    {
        int c0 = tid&255;
        float w1r[2][4], b1r[2];
        #pragma unroll
        for(int h=0;h<2;h++){
            int c = c0 + h*256;
            b1r[h] = b1[c];
            #pragma unroll
            for(int k=0;k<4;k++) w1r[h][k] = w1[k*512+c];
        }
        #pragma unroll 4
        for(int j=0;j<64;j++){
            int r = j>>1, h = j&1;
            int c = c0 + h*256;
            float v = 0.f;
            #pragma unroll
            for(int k=0;k<4;k++) v = fmaf(rs[r*4+k], w1r[h][k], v);
            v += b1r[h];
            hs[r*520+c] = f2bf(fmaxf(v,0.f));
        }
    }
    __syncthreads();
    int lane = tid&63, wave = tid>>6;
    int wm = (wave>>1)*16, wn = (wave&1)*32;
    int lr = lane&15, lq = lane>>4;
    float4v acc[2];
    #pragma unroll
    for(int j=0;j<2;j++){ acc[j].x=0.f; acc[j].y=0.f; acc[j].z=0.f; acc[j].w=0.f; }
    short8 pb[2][2];
    #pragma unroll
    for(int ni=0;ni<2;ni++)
        pb[0][ni] = *(const short8*)(w2T + (size_t)(n0+wn+ni*16+lr)*512 + lq*8);
    #pragma unroll
    for(int t=0;t<16;t++){
        const int cur = t&1;
        if(t<15){
            #pragma unroll
            for(int ni=0;ni<2;ni++)
                pb[cur^1][ni] = *(const short8*)(w2T + (size_t)(n0+wn+ni*16+lr)*512 + (t+1)*32 + lq*8);
        }
        short8 a0 = *(const short8*)(&hs[(wm+lr)*520 + t*32 + lq*8]);
        acc[0] = __builtin_amdgcn_mfma_f32_16x16x32_bf16(a0, pb[cur][0], acc[0], 0,0,0);
        acc[1] = __builtin_amdgcn_mfma_f32_16x16x32_bf16(a0, pb[cur][1], acc[1], 0,0,0);
    }
    #pragma unroll
    for(int rr=0;rr<4;rr++){
        int gm = m0+wm+lq*4+rr;
        #pragma unroll
        for(int ni=0;ni<2;ni++){
            int gn = n0+wn+ni*16+lr;
            pos[(size_t)gm*256+gn] = acc[ni][rr] + b2[gn];
        }
    }
}

// ================= MFMA bf16 GEMM (reg-staged double-buffered pipeline) =================
#define LSTR 40

template<int TM, int TN, bool ABF16, bool RELU, bool OUTBF16>
__global__ __launch_bounds__(256) void mfma_gemm_kernel(
    const void* __restrict__ Av, const void* __restrict__ A2v,
    const void* __restrict__ A3v, int nA2lim,
    const short* __restrict__ WT, size_t zWT,
    const float* __restrict__ b0, const float* __restrict__ b1,
    const float* __restrict__ b2, int ns1, int ns2, size_t zB,
    void* __restrict__ Cv, size_t zC, int M, int K, int N, int nxt)
{
    __shared__ short As[2][TM*LSTR];
    __shared__ short Bs[2][TN*LSTR];
    int zz, n0;
    if(nxt){ zz = blockIdx.x / nxt; n0 = (blockIdx.x % nxt)*TN; }
    else   { zz = blockIdx.z;       n0 = blockIdx.x*TN; }
    WT += (size_t)zz*zWT; b0 += (size_t)zz*zB; b1 += (size_t)zz*zB; b2 += (size_t)zz*zB;
    int tid = threadIdx.x;
    int lane = tid&63, wave = tid>>6;
    int m0 = blockIdx.y*TM;
    const int MI = TM/32;
    const int NI = TN/32;
    int wm = (wave>>1)*(TM/2), wn = (wave&1)*(TN/2);
    int lr = lane&15, lq = lane>>4;
    float4v acc[MI][NI];
    #pragma unroll
    for(int i=0;i<MI;i++)
        #pragma unroll
        for(int j=0;j<NI;j++){ acc[i][j].x=0.f; acc[i][j].y=0.f; acc[i][j].z=0.f; acc[i][j].w=0.f; }

    const float* Af; const float* Ad; const short* Ah;
    if(ABF16){ Ah = (const short*)Av; Af=nullptr; Ad=nullptr; }
    else {
        Af = (n0 < nA2lim)? (const float*)Av : (const float*)A3v;
        Ad = (n0 < nA2lim)? (const float*)A2v : nullptr;
        Ah = nullptr;
    }

    short8  rA16[ABF16? TM/64 : 1];
    float4v rAf [ABF16? 1 : TM/32];
    float4v rAd [ABF16? 1 : TM/32];
    short8  rB[TN/64];

    auto LOAD = [&](int k0){
        if constexpr(ABF16){
            #pragma unroll
            for(int it=0; it<TM/64; ++it){
                int idx=(it*256+tid)*8; int r=idx>>5, kk=idx&31; int gm=m0+r;
                short8 v = {};
                if(gm<M) v = *(const short8*)(Ah + (size_t)gm*K + (k0+kk));
                rA16[it]=v;
            }
        } else {
            #pragma unroll
            for(int it=0; it<TM/32; ++it){
                int idx=(it*256+tid)*4; int r=idx>>5, kk=idx&31; int gm=m0+r;
                float4v v; v.x=0.f;v.y=0.f;v.z=0.f;v.w=0.f;
                float4v w; w.x=0.f;w.y=0.f;w.z=0.f;w.w=0.f;
                if(gm<M){
                    v = *(const float4v*)(Af + (size_t)gm*K + (k0+kk));
                    if(Ad) w = *(const float4v*)(Ad + (size_t)gm*K + (k0+kk));
                }
                rAf[it]=v; rAd[it]=w;
            }
        }
        #pragma unroll
        for(int it=0; it<TN/64; ++it){
            int idx=(it*256+tid)*8; int r=idx>>5, kk=idx&31; int gn=n0+r;
            short8 v = {};
            if(gn<N) v = *(const short8*)(WT + (size_t)gn*K + (k0+kk));
            rB[it]=v;
        }
    };
    auto STORE = [&](int buf){
        if constexpr(ABF16){
            #pragma unroll
            for(int it=0; it<TM/64; ++it){
                int idx=(it*256+tid)*8; int r=idx>>5, kk=idx&31;
                *(short8*)(&As[buf][r*LSTR+kk]) = rA16[it];
            }
        } else {
            #pragma unroll
            for(int it=0; it<TM/32; ++it){
                int idx=(it*256+tid)*4; int r=idx>>5, kk=idx&31;
                float4v v = rAf[it];
                if(Ad){ v.x+=rAd[it].x; v.y+=rAd[it].y; v.z+=rAd[it].z; v.w+=rAd[it].w; }
                short4v h; h.x=f2bf(v.x); h.y=f2bf(v.y); h.z=f2bf(v.z); h.w=f2bf(v.w);
                *(short4v*)(&As[buf][r*LSTR+kk]) = h;
            }
        }
        #pragma unroll
        for(int it=0; it<TN/64; ++it){
            int idx=(it*256+tid)*8; int r=idx>>5, kk=idx&31;
            *(short8*)(&Bs[buf][r*LSTR+kk]) = rB[it];
        }
    };

    const int nt = K>>5;
    LOAD(0);
    STORE(0);
    __syncthreads();
    for(int t=0; t<nt; ++t){
        int cb = t&1;
        if(t+1<nt) LOAD((t+1)<<5);
        short8 af[MI], bfr[NI];
        #pragma unroll
        for(int mi=0;mi<MI;mi++) af[mi]  = *(const short8*)(&As[cb][(wm+mi*16+lr)*LSTR + lq*8]);
        #pragma unroll
        for(int ni=0;ni<NI;ni++) bfr[ni] = *(const short8*)(&Bs[cb][(wn+ni*16+lr)*LSTR + lq*8]);
        #pragma unroll
        for(int mi=0;mi<MI;mi++)
            #pragma unroll
            for(int ni=0;ni<NI;ni++)
                acc[mi][ni] = __builtin_amdgcn_mfma_f32_16x16x32_bf16(af[mi], bfr[ni], acc[mi][ni], 0,0,0);
        if(t+1<nt){
            STORE(cb^1);
            __syncthreads();
        }
    }
    float* Cf=(float*)Cv + (size_t)zz*zC; bf16* Ch=(bf16*)Cv + (size_t)zz*zC;
    #pragma unroll
    for(int mi=0;mi<MI;mi++){
        #pragma unroll
        for(int r=0;r<4;r++){
            int gm = m0+wm+mi*16+lq*4+r;
            if(gm>=M) continue;
            #pragma unroll
            for(int ni=0;ni<NI;ni++){
                int gn = n0+wn+ni*16+lr;
                if(gn>=N) continue;
                float bv = (gn<ns1)? b0[gn] : ((gn<ns2)? b1[gn-ns1] : b2[gn-ns2]);
                float v = acc[mi][ni][r] + bv;
                if(RELU) v = fmaxf(v,0.f);
                if(OUTBF16) Ch[(size_t)gm*N+gn]=__float2bfloat16(v);
                else        Cf[(size_t)gm*N+gn]=v;
            }
        }
    }
}

// ================= fused MHA (union LDS, vectorized staging, bf16 out) =================
__global__ __launch_bounds__(256) void fused_mha_kernel(
    const float* __restrict__ QKV, short* __restrict__ O)
{
    const int ld = 768;
    int bh = blockIdx.y; int b = bh>>3, h = bh&7;
    int q0 = blockIdx.x*64;
    __shared__ short lds[31104];   // 62208 B
    short* Vts = lds;              // 32 x 324
    short* Qs  = lds + 10368;      // 64 x 36
    short* Ks  = lds + 12672;      // 304 x 36
    short* Ps  = lds + 10368;      // 64 x 324, overlays Qs+Ks after S-phase
    int tid = threadIdx.x;
    for(int idx=tid; idx<64*8; idx+=256){
        int r=idx>>3, c4=(idx&7)*4; int gq=q0+r;
        float4v v; v.x=0.f;v.y=0.f;v.z=0.f;v.w=0.f;
        if(gq<NQ_) v = *(const float4v*)(QKV + ((size_t)(b*NQ_+gq))*ld + h*DH_ + c4);
        short4v h4; h4.x=f2bf(v.x);h4.y=f2bf(v.y);h4.z=f2bf(v.z);h4.w=f2bf(v.w);
        *(short4v*)(Qs + r*36 + c4) = h4;
    }
    for(int idx=tid; idx<304*8; idx+=256){
        int r=idx>>3, c4=(idx&7)*4;
        float4v v; v.x=0.f;v.y=0.f;v.z=0.f;v.w=0.f;
        if(r<NQ_) v = *(const float4v*)(QKV + 256 + ((size_t)(b*NQ_+r))*ld + h*DH_ + c4);
        short4v h4; h4.x=f2bf(v.x);h4.y=f2bf(v.y);h4.z=f2bf(v.z);h4.w=f2bf(v.w);
        *(short4v*)(Ks + r*36 + c4) = h4;
    }
    for(int idx=tid; idx<320*8; idx+=256){
        int r=idx>>3, c4=(idx&7)*4;
        float4v v; v.x=0.f;v.y=0.f;v.z=0.f;v.w=0.f;
        if(r<NQ_) v = *(const float4v*)(QKV + 512 + ((size_t)(b*NQ_+r))*ld + h*DH_ + c4);
        Vts[(c4+0)*324+r]=f2bf(v.x); Vts[(c4+1)*324+r]=f2bf(v.y);
        Vts[(c4+2)*324+r]=f2bf(v.z); Vts[(c4+3)*324+r]=f2bf(v.w);
    }
    __syncthreads();

    int lane = tid&63, wave = tid>>6;
    int lr = lane&15, lq = lane>>4;
    int mrow = wave*16;
    const float scale = 0.17677669529663687f;

    float4v acc[19];
    #pragma unroll
    for(int t=0;t<19;t++){ acc[t].x=0.f; acc[t].y=0.f; acc[t].z=0.f; acc[t].w=0.f; }
    short8 afrag = *(const short8*)(&Qs[(mrow+lr)*36 + lq*8]);
    #pragma unroll
    for(int t=0;t<19;t++){
        short8 bfrag = *(const short8*)(&Ks[(t*16+lr)*36 + lq*8]);
        acc[t] = __builtin_amdgcn_mfma_f32_16x16x32_bf16(afrag, bfrag, acc[t], 0,0,0);
    }
    __syncthreads();   // Qs/Ks dead; Ps overlay becomes writable

    for(int idx=tid; idx<64*16; idx+=256){
        int r=idx>>4, c=idx&15;
        Ps[r*324 + 304 + c]=0;
    }
    #pragma unroll
    for(int t=0;t<19;t++){
        #pragma unroll
        for(int r=0;r<4;r++) acc[t][r] *= scale;
    }
    if(lr>=12){
        #pragma unroll
        for(int r=0;r<4;r++) acc[18][r] = -1e30f;
    }
    float mx[4];
    #pragma unroll
    for(int r=0;r<4;r++){
        float m = acc[0][r];
        #pragma unroll
        for(int t=1;t<19;t++) m = fmaxf(m, acc[t][r]);
        m = fmaxf(m, __shfl_xor(m,1)); m = fmaxf(m, __shfl_xor(m,2));
        m = fmaxf(m, __shfl_xor(m,4)); m = fmaxf(m, __shfl_xor(m,8));
        mx[r]=m;
    }
    float sum[4] = {0.f,0.f,0.f,0.f};
    #pragma unroll
    for(int t=0;t<19;t++){
        #pragma unroll
        for(int r=0;r<4;r++){
            float p = __expf(acc[t][r]-mx[r]);
            acc[t][r]=p; sum[r]+=p;
        }
    }
    #pragma unroll
    for(int r=0;r<4;r++){
        float s = sum[r];
        s += __shfl_xor(s,1); s += __shfl_xor(s,2);
        s += __shfl_xor(s,4); s += __shfl_xor(s,8);
        sum[r] = 1.f/s;
    }
    #pragma unroll
    for(int t=0;t<19;t++){
        #pragma unroll
        for(int r=0;r<4;r++){
            Ps[(mrow + lq*4 + r)*324 + t*16 + lr] = f2bf(acc[t][r]*sum[r]);
        }
    }
    __syncthreads();
    float4v oacc[2];
    oacc[0].x=0.f;oacc[0].y=0.f;oacc[0].z=0.f;oacc[0].w=0.f;
    oacc[1]=oacc[0];
    #pragma unroll
    for(int kc=0;kc<10;kc++){
        short8 pa = *(const short8*)(&Ps[(mrow+lr)*324 + kc*32 + lq*8]);
        #pragma unroll
        for(int n=0;n<2;n++){
            short8 vb = *(const short8*)(&Vts[(n*16+lr)*324 + kc*32 + lq*8]);
            oacc[n] = __builtin_amdgcn_mfma_f32_16x16x32_bf16(pa, vb, oacc[n], 0,0,0);
        }
    }
    #pragma unroll
    for(int n=0;n<2;n++){
        #pragma unroll
        for(int r=0;r<4;r++){
            int gq = q0 + mrow + lq*4 + r;
            if(gq<NQ_)
                O[((size_t)(b*NQ_+gq))*D_ + h*DH_ + n*16 + lr] = f2bf(oacc[n][r]);
        }
    }
}

// ============== all-weights transpose f32[K][N] -> bf16[N][K] ==============
#define NTD 74
struct TD { const float* src; unsigned dstoff; int K, N, base; };
struct TAll { TD d[NTD]; };

__global__ __launch_bounds__(256) void transpose_all_kernel(TAll p, short* __restrict__ WTb){
    int blk = blockIdx.x;
    int di = 0;
    #pragma unroll 1
    for(int i=0;i<NTD;i++){ if(blk >= p.d[i].base) di = i; }
    TD d = p.d[di];
    int rel = blk - d.base;
    int ntx = (d.N+31)/32;
    int tn = (rel % ntx)*32, tk = (rel / ntx)*32;
    __shared__ float t[32][33];
    int tx = threadIdx.x&31, ty = threadIdx.x>>5;
    for(int i=0;i<32;i+=8){
        int k = tk+ty+i, n = tn+tx;
        t[ty+i][tx] = (k<d.K && n<d.N)? d.src[(size_t)k*d.N+n] : 0.f;
    }
    __syncthreads();
    short* out = WTb + d.dstoff;
    for(int i=0;i<32;i+=8){
        int n = tn+ty+i, k = tk+tx;
        if(n<d.N && k<d.K) out[(size_t)n*d.K+k] = f2bf(t[tx][ty+i]);
    }
}

// ---------------- small elementwise kernels ----------------
__global__ void copy_kernel(const float* __restrict__ a, float* __restrict__ o, int n){
    int i = blockIdx.x*blockDim.x+threadIdx.x;
    if(i<n) o[i]=a[i];
}
__global__ void cvt_f32_bf16_kernel(const float* __restrict__ a, short* __restrict__ o, int n4){
    int i = blockIdx.x*blockDim.x+threadIdx.x;
    if(i<n4){
        float4v v = *(const float4v*)(a + (size_t)i*4);
        short4v h; h.x=f2bf(v.x); h.y=f2bf(v.y); h.z=f2bf(v.z); h.w=f2bf(v.w);
        *(short4v*)(o + (size_t)i*4) = h;
    }
}
__global__ void sigmoid_init_kernel(const float* __restrict__ a, float* __restrict__ o, int n){
    int i = blockIdx.x*blockDim.x+threadIdx.x;
    if(i<n){ float x=a[i]; o[i]=1.f/(1.f+expf(-x)); }
}
__global__ void write_out_kernel(const float* __restrict__ refd, const float* __restrict__ logits, float* __restrict__ out){
    int i = blockIdx.x*blockDim.x+threadIdx.x;
    if(i<BN_*4) out[i]=refd[i];
    else if(i<BN_*4+BN_*NCLS_) out[i]=logits[i-BN_*4];
}

// ---------------- layernorm with residual (t2 bf16), optional bf16 copy-out ----------------
__global__ __launch_bounds__(256) void ln_residual_kernel(
    float* __restrict__ cur, const short* __restrict__ t2b,
    const float* __restrict__ g, const float* __restrict__ b,
    short* __restrict__ cb)
{
    int row = blockIdx.x; int c = threadIdx.x;
    size_t idx = (size_t)row*D_+c;
    float x = cur[idx] + bf2f(t2b[idx]);
    float v1 = x, v2 = x*x;
    #pragma unroll
    for(int o=32;o>0;o>>=1){ v1 += __shfl_down(v1,o,64); v2 += __shfl_down(v2,o,64); }
    __shared__ float s1[4], s2[4], st[2];
    int wid=c>>6, lane=c&63;
    if(lane==0){ s1[wid]=v1; s2[wid]=v2; }
    __syncthreads();
    if(c==0){
        float a=0,d=0;
        #pragma unroll
        for(int i=0;i<4;i++){a+=s1[i]; d+=s2[i];}
        st[0]=a/(float)D_; st[1]=d/(float)D_;
    }
    __syncthreads();
    float m=st[0], var=st[1]-m*m;
    float y = (x-m)*rsqrtf(var+1e-5f)*g[c] + b[c];
    cur[idx]=y;
    if(cb) cb[idx]=f2bf(y);
}

// ---------------- deformable sampling (fused attw softmax, bf16 out) ----------------
__global__ __launch_bounds__(256) void deform_sample_kernel(
    const float* __restrict__ refd, const float* __restrict__ oab,
    const bf16* __restrict__ value, short* __restrict__ outacc)
{
    int row = blockIdx.x; int b = row/NQ_;
    int tid = threadIdx.x; int h = tid>>5, c = tid&31;
    __shared__ float so[192], sa[96], sr[4];
    if(tid<192) so[tid]=oab[(size_t)row*288+tid];
    if(tid<96)  sa[tid]=oab[(size_t)row*288+192+tid];
    if(tid<4)   sr[tid]=refd[(size_t)row*4+tid];
    __syncthreads();
    if(tid<8){
        float* p = sa + tid*12;
        float m=-1e30f;
        #pragma unroll
        for(int i2=0;i2<12;i2++) m=fmaxf(m,p[i2]);
        float s=0.f;
        #pragma unroll
        for(int i2=0;i2<12;i2++){ float e=__expf(p[i2]-m); p[i2]=e; s+=e; }
        float inv=1.f/s;
        #pragma unroll
        for(int i2=0;i2<12;i2++) p[i2]*=inv;
    }
    __syncthreads();
    float cx=sr[0], cy=sr[1], rw=sr[2], rh=sr[3];
    const int HS[3]={80,40,20}, WS[3]={80,40,20}, ST[3]={0,6400,8000};
    float acc=0.f;
    const bf16* vb = value + (size_t)b*LM_*D_ + h*DH_ + c;
    for(int lv=0;lv<3;lv++){
        int Hl=HS[lv], Wl=WS[lv], st=ST[lv];
        #pragma unroll
        for(int pt=0;pt<4;pt++){
            int oi = ((h*3+lv)*4+pt)*2;
            float ox=so[oi], oy=so[oi+1];
            float wa=sa[h*12+lv*4+pt];
            float lx = cx + ox*0.25f*rw*0.5f;
            float ly = cy + oy*0.25f*rh*0.5f;
            float x = lx*(float)Wl - 0.5f, y = ly*(float)Hl - 0.5f;
            float x0f=floorf(x), y0f=floorf(y);
            float wx=x-x0f, wy=y-y0f;
            int x0=(int)x0f, y0=(int)y0f;
            #pragma unroll
            for(int dy=0;dy<2;dy++){
                #pragma unroll
                for(int dx=0;dx<2;dx++){
                    int xi=x0+dx, yi=y0+dy;
                    if(xi>=0 && xi<Wl && yi>=0 && yi<Hl){
                        float w = (dx? wx : 1.f-wx)*(dy? wy : 1.f-wy);
                        int lin = yi*Wl+xi;
                        acc += __bfloat162float(vb[(size_t)(st+lin)*D_]) * (w*wa);
                    }
                }
            }
        }
    }
    outacc[(size_t)row*D_+tid]=f2bf(acc);
}

// ---------------- host helpers ----------------
// tail GEMM dispatcher: TM=64, TN=64
static void g64x(const void*A, const void*A2, const void*A3, int nA2lim,
                 const short*WT, const float*b0, const float*b1, const float*b2,
                 int ns1, int ns2, void*C, int M,int K,int N,
                 bool abf16, bool relu, bool outbf, hipStream_t s){
    dim3 g((N+63)/64,(M+63)/64,1);
    #define CALLG(AB,RL,OB) mfma_gemm_kernel<64,64,AB,RL,OB><<<g,256,0,s>>>(A,A2,A3,nA2lim,WT,0,b0,b1,b2,ns1,ns2,0,C,0,M,K,N,0)
    if(abf16){
        if(relu){ if(outbf) CALLG(true,true,true);  else CALLG(true,true,false); }
        else    { if(outbf) CALLG(true,false,true); else CALLG(true,false,false); }
    } else {
        if(relu){ if(outbf) CALLG(false,true,true);  else CALLG(false,true,false); }
        else    { if(outbf) CALLG(false,false,true); else CALLG(false,false,false); }
    }
    #undef CALLG
}
static void g64(const float*A, const float*A2, const float*A3, int nA2lim,
                const short*WT, const float*b0, const float*b1, const float*b2,
                int ns1, int ns2, void*C, int M,int K,int N,
                bool relu, bool outbf, hipStream_t s){
    g64x(A,A2,A3,nA2lim,WT,b0,b1,b2,ns1,ns2,C,M,K,N,false,relu,outbf,s);
}
static void g64b(const short*A, const short*WT, const float*b, void*C,
                 int M,int K,int N, hipStream_t s){
    g64x(A,nullptr,nullptr,1<<30,WT,b,b,b,N,N+1,C,M,K,N,true,false,true,s);
}
static int ntiles(int K,int N){ return ((N+31)/32)*((K+31)/32); }

extern "C" void kernel_launch(void* const* d_in, const int* in_sizes, int n_in,
                              void* d_out, int out_size, void* d_ws, size_t ws_size,
                              hipStream_t stream) {
    const float* tgt   = (const float*)d_in[0];
    const float* rpu   = (const float*)d_in[1];
    const float* mem   = (const float*)d_in[2];
    const float* sa_wq = (const float*)d_in[3];
    const float* sa_wk = (const float*)d_in[4];
    const float* sa_wv = (const float*)d_in[5];
    const float* sa_wo = (const float*)d_in[6];
    const float* val_w = (const float*)d_in[7];
    const float* out_w = (const float*)d_in[8];
    const float* bb_w1 = (const float*)d_in[9];
    const float* bb_w2 = (const float*)d_in[10];
    const float* sa_bq = (const float*)d_in[11];
    const float* sa_bk = (const float*)d_in[12];
    const float* sa_bv = (const float*)d_in[13];
    const float* sa_bo = (const float*)d_in[14];
    const float* ln1_b = (const float*)d_in[15];
    const float* ln2_b = (const float*)d_in[16];
    const float* ln3_b = (const float*)d_in[17];
    const float* val_b = (const float*)d_in[18];
    const float* out_b = (const float*)d_in[19];
    const float* ffn_b2= (const float*)d_in[20];
    const float* bb_b1 = (const float*)d_in[21];
    const float* bb_b2 = (const float*)d_in[22];
    const float* ln1_g = (const float*)d_in[23];
    const float* ln2_g = (const float*)d_in[24];
    const float* ln3_g = (const float*)d_in[25];
    const float* off_w = (const float*)d_in[26];
    const float* off_b = (const float*)d_in[27];
    const float* attw_w= (const float*)d_in[28];
    const float* attw_b= (const float*)d_in[29];
    const float* ffn_w1= (const float*)d_in[30];
    const float* ffn_b1= (const float*)d_in[31];
    const float* ffn_w2= (const float*)d_in[32];
    const float* bb_w3 = (const float*)d_in[33];
    const float* bb_b3 = (const float*)d_in[34];
    const float* sc_w  = (const float*)d_in[35];
    const float* sc_b  = (const float*)d_in[36];
    const float* qp_w1 = (const float*)d_in[37];
    const float* qp_b1 = (const float*)d_in[38];
    const float* qp_w2 = (const float*)d_in[39];
    const float* qp_b2 = (const float*)d_in[40];

    const size_t BND = (size_t)BN_*D_;          // 1,228,800
    const size_t USZ = (size_t)BN_*DFF_;        // 4,915,200 floats (union)
    const size_t LMD = (size_t)BS_*LM_*D_;      // 34,406,400
    const size_t LSZ = 1122304;                 // WT shorts per layer

    float* ws   = (float*)d_ws;
    float* cur  = ws;
    float* pos  = cur + BND;
    float* refd = pos + BND;
    float* U    = refd + (size_t)BN_*4;
    short* tmp16 = (short*)(U + USZ);
    short* t216  = tmp16 + BND;
    short* WT    = t216 + BND;
    short* qp2T  = WT + 6*LSZ;
    short* scT   = qp2T + 131072;
    short* X     = scT + 20480;
    // U aliases (phase-disjoint)
    float* QKVh   = U;
    float* offsb  = U;
    short* ffnh16 = (short*)U;
    float* logitsb= U;
    short* curb = tmp16;

    size_t offX = (size_t)((char*)X - (char*)d_ws);
    int vmode;
    if(ws_size >= offX + 7*LMD*2)      vmode = 3;
    else if(ws_size >= offX + 6*LMD*2) vmode = 2;
    else if(ws_size >= offX + 4*LMD)   vmode = 1;
    else                               vmode = 0;
    short* memT   = X;
    short* values = (vmode==3)? X + LMD : X;
    short* value1 = X + LMD;
    short* value0 = X;

    const int nBN_D = (int)BND;
    copy_kernel<<<(nBN_D+255)/256,256,0,stream>>>(tgt, cur, nBN_D);
    sigmoid_init_kernel<<<(BN_*4+255)/256,256,0,stream>>>(rpu, refd, BN_*4);
    if(vmode==1 || vmode==3){
        int n4 = (int)(LMD/4);
        cvt_f32_bf16_kernel<<<(n4+255)/256,256,0,stream>>>(mem, memT, n4);
    }

    // ---- transpose ALL weights upfront (one launch) ----
    {
        TAll tp; int base=0; int di=0;
        const size_t offs[12] = { 0,65536,131072,196608,262144,327680,
                                  393216,442368,466944,729088,991232,1056768 };
        const int Ks[12] = { 256,256,256,256,256,256,256,256,256,1024,256,256 };
        const int Ns[12] = { 256,256,256,256,256,256,192,96,1024,256,256,256 };
        for(int l=0;l<NLAYERS_;l++){
            const float* srcs[12] = { sa_wq+(size_t)l*D_*D_, sa_wk+(size_t)l*D_*D_, sa_wv+(size_t)l*D_*D_,
                                      sa_wo+(size_t)l*D_*D_, val_w+(size_t)l*D_*D_, out_w+(size_t)l*D_*D_,
                                      off_w+(size_t)l*D_*192, attw_w+(size_t)l*D_*96,
                                      ffn_w1+(size_t)l*D_*DFF_, ffn_w2+(size_t)l*DFF_*D_,
                                      bb_w1+(size_t)l*D_*D_, bb_w2+(size_t)l*D_*D_ };
            for(int j=0;j<12;j++){
                tp.d[di] = { srcs[j], (unsigned)(l*LSZ + offs[j]), Ks[j], Ns[j], base };
                base += ntiles(Ks[j],Ns[j]); di++;
            }
        }
        tp.d[di] = { qp_w2, (unsigned)(6*LSZ), 512, 256, base }; base += ntiles(512,256); di++;
        tp.d[di] = { sc_w + (size_t)(NLAYERS_-1)*D_*NCLS_, (unsigned)(6*LSZ+131072), 256, 80, base }; base += ntiles(256,80); di++;
        transpose_all_kernel<<<base,256,0,stream>>>(tp, WT);
    }

    // ---- value projections (TM=128 pipelined, z-folded — verified 389 µs config) ----
    if(vmode==3){
        dim3 g(12,1050,1);
        mfma_gemm_kernel<128,128,true,false,true><<<g,256,0,stream>>>(
            memT,nullptr,nullptr,1<<30, WT+262144, LSZ,
            val_b,val_b,val_b, 256,257, 256, values, LMD, BS_*LM_, D_, D_, 2);
    } else if(vmode==2){
        dim3 g(12,1050,1);
        mfma_gemm_kernel<128,128,false,false,true><<<g,256,0,stream>>>(
            mem,nullptr,mem,1<<30, WT+262144, LSZ,
            val_b,val_b,val_b, 256,257, 256, values, LMD, BS_*LM_, D_, D_, 2);
    }

    for(int i=0;i<NLAYERS_;i++){
        const bf16* value_i;
        if(vmode>=2) value_i = (const bf16*)(values + (size_t)i*LMD);
        else {
            dim3 g(2,1050,1);
            if(vmode==1){
                mfma_gemm_kernel<128,128,true,false,true><<<g,256,0,stream>>>(
                    memT,nullptr,nullptr,1<<30, WT+i*LSZ+262144, 0,
                    val_b+(size_t)i*D_,val_b,val_b, 256,257, 0, value1, 0, BS_*LM_, D_, D_, 0);
                value_i = (const bf16*)value1;
            } else {
                mfma_gemm_kernel<128,128,false,false,true><<<g,256,0,stream>>>(
                    mem,nullptr,mem,1<<30, WT+i*LSZ+262144, 0,
                    val_b+(size_t)i*D_,val_b,val_b, 256,257, 0, value0, 0, BS_*LM_, D_, D_, 0);
                value_i = (const bf16*)value0;
            }
        }
        // pos = MLP2(refd) — fused single kernel
        pos_mlp_kernel<<<dim3(4,150),256,0,stream>>>(refd, qp_w1, qp_b1, qp2T, qp_b2, pos);
        // QKV fused: Q,K from cur+pos (n<512), V from cur
        g64(cur, pos, cur, 512, WT+i*LSZ,
            sa_bq+(size_t)i*D_, sa_bk+(size_t)i*D_, sa_bv+(size_t)i*D_, 256, 512,
            QKVh, BN_, D_, 768, false,false, stream);
        {
            dim3 g((NQ_+63)/64, BS_*NHEAD_);
            fused_mha_kernel<<<g,256,0,stream>>>(QKVh, tmp16);
        }
        g64b(tmp16, WT+i*LSZ+196608, sa_bo+(size_t)i*D_, t216, BN_, D_, D_, stream);
        ln_residual_kernel<<<BN_,256,0,stream>>>(cur, t216, ln1_g+(size_t)i*D_, ln1_b+(size_t)i*D_, nullptr);
        // deformable attention: fused off|attw projection from cur+pos
        g64(cur, pos, cur, 1<<30, WT+i*LSZ+393216,
            off_b+(size_t)i*192, attw_b+(size_t)i*96, attw_b+(size_t)i*96, 192, 288,
            offsb, BN_, D_, 288, false,false, stream);
        deform_sample_kernel<<<BN_,256,0,stream>>>(refd, offsb, value_i, tmp16);
        g64b(tmp16, WT+i*LSZ+327680, out_b+(size_t)i*D_, t216, BN_, D_, D_, stream);
        ln_residual_kernel<<<BN_,256,0,stream>>>(cur, t216, ln2_g+(size_t)i*D_, ln2_b+(size_t)i*D_, curb);
        // FFN: A = bf16 cur (from ln2), hidden bf16, FFN2 bf16-A
        g64x(curb,nullptr,nullptr,1<<30, WT+i*LSZ+466944, ffn_b1+(size_t)i*DFF_,ffn_b1,ffn_b1, DFF_,DFF_+1,
             ffnh16, BN_, D_, DFF_, true,true,true, stream);
        g64x(ffnh16,nullptr,nullptr,1<<30, WT+i*LSZ+729088, ffn_b2+(size_t)i*D_,ffn_b2,ffn_b2, 256,257,
             t216, BN_, DFF_, D_, true,false,true, stream);
        ln_residual_kernel<<<BN_,256,0,stream>>>(cur, t216, ln3_g+(size_t)i*D_, ln3_b+(size_t)i*D_, curb);
        // bbox head — single fused kernel (bb1+bb2+bb3+update)
        bbox_head_kernel<<<BN_/16,256,0,stream>>>(curb,
            WT+i*LSZ+991232, bb_b1+(size_t)i*D_,
            WT+i*LSZ+1056768, bb_b2+(size_t)i*D_,
            bb_w3+(size_t)i*D_*4, bb_b3+(size_t)i*4, refd);
    }
    // final score GEMM: A = bf16 cur (curb from layer-5 ln3)
    g64x(curb,nullptr,nullptr,1<<30, scT, sc_b+(size_t)(NLAYERS_-1)*NCLS_,sc_b,sc_b, NCLS_,NCLS_+1,
         logitsb, BN_, D_, NCLS_, true,false,false, stream);
    int tot = BN_*4 + BN_*NCLS_;
    write_out_kernel<<<(tot+255)/256,256,0,stream>>>(refd, logitsb, (float*)d_out);
}

// Round 9
// 2072.256 us; speedup vs baseline: 1.1717x; 1.0457x over previous
//
#include <hip/hip_runtime.h>
#include <hip/hip_bf16.h>

typedef __hip_bfloat16 bf16;
typedef short short8 __attribute__((ext_vector_type(8)));
typedef short short4v __attribute__((ext_vector_type(4)));
typedef float float4v __attribute__((ext_vector_type(4)));

#define D_ 256
#define NHEAD_ 8
#define DH_ 32
#define NQ_ 300
#define NLAYERS_ 6
#define DFF_ 1024
#define NCLS_ 80
#define BS_ 16
#define LM_ 8400
#define BN_ (BS_*NQ_)   // 4800

static __device__ __forceinline__ short f2bf(float x){
    union{float f; unsigned u;} v; v.f = x;
    unsigned r = v.u + 0x7FFF + ((v.u>>16)&1);
    return (short)(r>>16);
}
static __device__ __forceinline__ float bf2f(short s){
    union{unsigned u; float f;} v; v.u = ((unsigned)(unsigned short)s)<<16; return v.f;
}

// ================= fused bbox head: refd = sigmoid(mlp3(curb) + inv_sig(refd)) =================
__global__ __launch_bounds__(256) void bbox_head_kernel(
    const short* __restrict__ curb,
    const short* __restrict__ w1T, const float* __restrict__ b1,
    const short* __restrict__ w2T, const float* __restrict__ b2,
    const float* __restrict__ w3, const float* __restrict__ b3,
    float* __restrict__ refd)
{
    __shared__ short h1[16*264];
    __shared__ float h2[16*260];
    int m0 = blockIdx.x*16;
    int tid = threadIdx.x, lane = tid&63, wave = tid>>6;
    int lr = lane&15, lq = lane>>4;
    int n0 = wave*64;
    short8 af[8];
    #pragma unroll
    for(int kt=0;kt<8;kt++)
        af[kt] = *(const short8*)(curb + (size_t)(m0+lr)*256 + kt*32 + lq*8);
    float4v acc[4];
    #pragma unroll
    for(int nf=0;nf<4;nf++){ acc[nf].x=0.f; acc[nf].y=0.f; acc[nf].z=0.f; acc[nf].w=0.f; }
    #pragma unroll
    for(int kt=0;kt<8;kt++){
        #pragma unroll
        for(int nf=0;nf<4;nf++){
            short8 bfr = *(const short8*)(w1T + (size_t)(n0+nf*16+lr)*256 + kt*32 + lq*8);
            acc[nf] = __builtin_amdgcn_mfma_f32_16x16x32_bf16(af[kt], bfr, acc[nf], 0,0,0);
        }
    }
    #pragma unroll
    for(int nf=0;nf<4;nf++){
        #pragma unroll
        for(int rr=0;rr<4;rr++){
            int row = lq*4+rr, gn = n0+nf*16+lr;
            float v = acc[nf][rr] + b1[gn];
            v = fmaxf(v,0.f);
            ((bf16*)h1)[row*264+gn] = __float2bfloat16(v);
        }
    }
    __syncthreads();
    #pragma unroll
    for(int nf=0;nf<4;nf++){ acc[nf].x=0.f; acc[nf].y=0.f; acc[nf].z=0.f; acc[nf].w=0.f; }
    #pragma unroll
    for(int kt=0;kt<8;kt++){
        short8 a2 = *(const short8*)(&h1[lr*264 + kt*32 + lq*8]);
        #pragma unroll
        for(int nf=0;nf<4;nf++){
            short8 bfr = *(const short8*)(w2T + (size_t)(n0+nf*16+lr)*256 + kt*32 + lq*8);
            acc[nf] = __builtin_amdgcn_mfma_f32_16x16x32_bf16(a2, bfr, acc[nf], 0,0,0);
        }
    }
    #pragma unroll
    for(int nf=0;nf<4;nf++){
        #pragma unroll
        for(int rr=0;rr<4;rr++){
            int row = lq*4+rr, gn = n0+nf*16+lr;
            float v = acc[nf][rr] + b2[gn];
            h2[row*260+gn] = fmaxf(v,0.f);
        }
    }
    __syncthreads();
    {
        int row = tid>>4, sub = tid&15;
        int n = sub>>2, kq = sub&3;
        float p = 0.f;
        const float* hr = h2 + row*260 + kq*64;
        #pragma unroll
        for(int k=0;k<64;k++) p = fmaf(hr[k], w3[(kq*64+k)*4+n], p);
        p += __shfl_xor(p,1);
        p += __shfl_xor(p,2);
        if(kq==0){
            float delta = p + b3[n];
            size_t idx = (size_t)(m0+row)*4+n;
            float x = refd[idx];
            x = fminf(fmaxf(x,0.f),1.f);
            float num = fmaxf(x,1e-5f), den = fmaxf(1.f-x,1e-5f);
            float nd = delta + logf(num/den);
            refd[idx] = 1.f/(1.f+expf(-nd));
        }
    }
}

// ================= fused pos MLP: pos = relu(refd@w1+b1)@w2 + b2 ; qpb = bf16(cur+pos) =================
__global__ __launch_bounds__(256) void pos_mlp_kernel(
    const float* __restrict__ refd, const float* __restrict__ w1, const float* __restrict__ b1,
    const short* __restrict__ w2T, const float* __restrict__ b2,
    const float* __restrict__ cur, float* __restrict__ pos, short* __restrict__ qpb)
{
    __shared__ short hs[32*520];
    __shared__ float rs[32*4];
    int n0 = blockIdx.x*64, m0 = blockIdx.y*32;
    int tid = threadIdx.x;
    if(tid<128) rs[tid] = refd[(size_t)m0*4 + tid];
    __syncthreads();
    {
        int c0 = tid&255;
        float w1r[2][4], b1r[2];
        #pragma unroll
        for(int h=0;h<2;h++){
            int c = c0 + h*256;
            b1r[h] = b1[c];
            #pragma unroll
            for(int k=0;k<4;k++) w1r[h][k] = w1[k*512+c];
        }
        #pragma unroll 4
        for(int j=0;j<64;j++){
            int r = j>>1, h = j&1;
            int c = c0 + h*256;
            float v = 0.f;
            #pragma unroll
            for(int k=0;k<4;k++) v = fmaf(rs[r*4+k], w1r[h][k], v);
            v += b1r[h];
            hs[r*520+c] = f2bf(fmaxf(v,0.f));
        }
    }
    __syncthreads();
    int lane = tid&63, wave = tid>>6;
    int wm = (wave>>1)*16, wn = (wave&1)*32;
    int lr = lane&15, lq = lane>>4;
    float4v acc[2];
    #pragma unroll
    for(int j=0;j<2;j++){ acc[j].x=0.f; acc[j].y=0.f; acc[j].z=0.f; acc[j].w=0.f; }
    short8 pb[2][2];
    #pragma unroll
    for(int ni=0;ni<2;ni++)
        pb[0][ni] = *(const short8*)(w2T + (size_t)(n0+wn+ni*16+lr)*512 + lq*8);
    #pragma unroll
    for(int t=0;t<16;t++){
        const int cur2 = t&1;
        if(t<15){
            #pragma unroll
            for(int ni=0;ni<2;ni++)
                pb[cur2^1][ni] = *(const short8*)(w2T + (size_t)(n0+wn+ni*16+lr)*512 + (t+1)*32 + lq*8);
        }
        short8 a0 = *(const short8*)(&hs[(wm+lr)*520 + t*32 + lq*8]);
        acc[0] = __builtin_amdgcn_mfma_f32_16x16x32_bf16(a0, pb[cur2][0], acc[0], 0,0,0);
        acc[1] = __builtin_amdgcn_mfma_f32_16x16x32_bf16(a0, pb[cur2][1], acc[1], 0,0,0);
    }
    #pragma unroll
    for(int rr=0;rr<4;rr++){
        int gm = m0+wm+lq*4+rr;
        #pragma unroll
        for(int ni=0;ni<2;ni++){
            int gn = n0+wn+ni*16+lr;
            size_t idx = (size_t)gm*256+gn;
            float p = acc[ni][rr] + b2[gn];
            pos[idx] = p;
            qpb[idx] = f2bf(cur[idx] + p);
        }
    }
}

// ================= MFMA bf16 GEMM (reg-staged double-buffered pipeline) =================
// ABF16 path: A-select by n0 (Av for n0<nA2lim, A3v otherwise), mirroring the f32 path.
#define LSTR 40

template<int TM, int TN, bool ABF16, bool RELU, bool OUTBF16>
__global__ __launch_bounds__(256) void mfma_gemm_kernel(
    const void* __restrict__ Av, const void* __restrict__ A2v,
    const void* __restrict__ A3v, int nA2lim,
    const short* __restrict__ WT, size_t zWT,
    const float* __restrict__ b0, const float* __restrict__ b1,
    const float* __restrict__ b2, int ns1, int ns2, size_t zB,
    void* __restrict__ Cv, size_t zC, int M, int K, int N, int nxt)
{
    __shared__ short As[2][TM*LSTR];
    __shared__ short Bs[2][TN*LSTR];
    int zz, n0;
    if(nxt){ zz = blockIdx.x / nxt; n0 = (blockIdx.x % nxt)*TN; }
    else   { zz = blockIdx.z;       n0 = blockIdx.x*TN; }
    WT += (size_t)zz*zWT; b0 += (size_t)zz*zB; b1 += (size_t)zz*zB; b2 += (size_t)zz*zB;
    int tid = threadIdx.x;
    int lane = tid&63, wave = tid>>6;
    int m0 = blockIdx.y*TM;
    const int MI = TM/32;
    const int NI = TN/32;
    int wm = (wave>>1)*(TM/2), wn = (wave&1)*(TN/2);
    int lr = lane&15, lq = lane>>4;
    float4v acc[MI][NI];
    #pragma unroll
    for(int i=0;i<MI;i++)
        #pragma unroll
        for(int j=0;j<NI;j++){ acc[i][j].x=0.f; acc[i][j].y=0.f; acc[i][j].z=0.f; acc[i][j].w=0.f; }

    const float* Af; const float* Ad; const short* Ah;
    if(ABF16){
        Ah = (n0 < nA2lim)? (const short*)Av : (const short*)A3v;
        Af=nullptr; Ad=nullptr;
    } else {
        Af = (n0 < nA2lim)? (const float*)Av : (const float*)A3v;
        Ad = (n0 < nA2lim)? (const float*)A2v : nullptr;
        Ah = nullptr;
    }

    short8  rA16[ABF16? TM/64 : 1];
    float4v rAf [ABF16? 1 : TM/32];
    float4v rAd [ABF16? 1 : TM/32];
    short8  rB[TN/64];

    auto LOAD = [&](int k0){
        if constexpr(ABF16){
            #pragma unroll
            for(int it=0; it<TM/64; ++it){
                int idx=(it*256+tid)*8; int r=idx>>5, kk=idx&31; int gm=m0+r;
                short8 v = {};
                if(gm<M) v = *(const short8*)(Ah + (size_t)gm*K + (k0+kk));
                rA16[it]=v;
            }
        } else {
            #pragma unroll
            for(int it=0; it<TM/32; ++it){
                int idx=(it*256+tid)*4; int r=idx>>5, kk=idx&31; int gm=m0+r;
                float4v v; v.x=0.f;v.y=0.f;v.z=0.f;v.w=0.f;
                float4v w; w.x=0.f;w.y=0.f;w.z=0.f;w.w=0.f;
                if(gm<M){
                    v = *(const float4v*)(Af + (size_t)gm*K + (k0+kk));
                    if(Ad) w = *(const float4v*)(Ad + (size_t)gm*K + (k0+kk));
                }
                rAf[it]=v; rAd[it]=w;
            }
        }
        #pragma unroll
        for(int it=0; it<TN/64; ++it){
            int idx=(it*256+tid)*8; int r=idx>>5, kk=idx&31; int gn=n0+r;
            short8 v = {};
            if(gn<N) v = *(const short8*)(WT + (size_t)gn*K + (k0+kk));
            rB[it]=v;
        }
    };
    auto STORE = [&](int buf){
        if constexpr(ABF16){
            #pragma unroll
            for(int it=0; it<TM/64; ++it){
                int idx=(it*256+tid)*8; int r=idx>>5, kk=idx&31;
                *(short8*)(&As[buf][r*LSTR+kk]) = rA16[it];
            }
        } else {
            #pragma unroll
            for(int it=0; it<TM/32; ++it){
                int idx=(it*256+tid)*4; int r=idx>>5, kk=idx&31;
                float4v v = rAf[it];
                if(Ad){ v.x+=rAd[it].x; v.y+=rAd[it].y; v.z+=rAd[it].z; v.w+=rAd[it].w; }
                short4v h; h.x=f2bf(v.x); h.y=f2bf(v.y); h.z=f2bf(v.z); h.w=f2bf(v.w);
                *(short4v*)(&As[buf][r*LSTR+kk]) = h;
            }
        }
        #pragma unroll
        for(int it=0; it<TN/64; ++it){
            int idx=(it*256+tid)*8; int r=idx>>5, kk=idx&31;
            *(short8*)(&Bs[buf][r*LSTR+kk]) = rB[it];
        }
    };

    const int nt = K>>5;
    LOAD(0);
    STORE(0);
    __syncthreads();
    for(int t=0; t<nt; ++t){
        int cb = t&1;
        if(t+1<nt) LOAD((t+1)<<5);
        short8 af[MI], bfr[NI];
        #pragma unroll
        for(int mi=0;mi<MI;mi++) af[mi]  = *(const short8*)(&As[cb][(wm+mi*16+lr)*LSTR + lq*8]);
        #pragma unroll
        for(int ni=0;ni<NI;ni++) bfr[ni] = *(const short8*)(&Bs[cb][(wn+ni*16+lr)*LSTR + lq*8]);
        #pragma unroll
        for(int mi=0;mi<MI;mi++)
            #pragma unroll
            for(int ni=0;ni<NI;ni++)
                acc[mi][ni] = __builtin_amdgcn_mfma_f32_16x16x32_bf16(af[mi], bfr[ni], acc[mi][ni], 0,0,0);
        if(t+1<nt){
            STORE(cb^1);
            __syncthreads();
        }
    }
    float* Cf=(float*)Cv + (size_t)zz*zC; bf16* Ch=(bf16*)Cv + (size_t)zz*zC;
    #pragma unroll
    for(int mi=0;mi<MI;mi++){
        #pragma unroll
        for(int r=0;r<4;r++){
            int gm = m0+wm+mi*16+lq*4+r;
            if(gm>=M) continue;
            #pragma unroll
            for(int ni=0;ni<NI;ni++){
                int gn = n0+wn+ni*16+lr;
                if(gn>=N) continue;
                float bv = (gn<ns1)? b0[gn] : ((gn<ns2)? b1[gn-ns1] : b2[gn-ns2]);
                float v = acc[mi][ni][r] + bv;
                if(RELU) v = fmaxf(v,0.f);
                if(OUTBF16) Ch[(size_t)gm*N+gn]=__float2bfloat16(v);
                else        Cf[(size_t)gm*N+gn]=v;
            }
        }
    }
}

// ================= fused MHA (bf16 QKV input, union LDS, bf16 out) =================
__global__ __launch_bounds__(256) void fused_mha_kernel(
    const short* __restrict__ QKV, short* __restrict__ O)
{
    const int ld = 768;
    int bh = blockIdx.y; int b = bh>>3, h = bh&7;
    int q0 = blockIdx.x*64;
    __shared__ short lds[31104];   // 62208 B
    short* Vts = lds;              // 32 x 324
    short* Qs  = lds + 10368;      // 64 x 36
    short* Ks  = lds + 12672;      // 304 x 36
    short* Ps  = lds + 10368;      // 64 x 324, overlays Qs+Ks after S-phase
    int tid = threadIdx.x;
    for(int idx=tid; idx<64*4; idx+=256){
        int r=idx>>2, c8=(idx&3)*8; int gq=q0+r;
        short8 v = {};
        if(gq<NQ_) v = *(const short8*)(QKV + (size_t)(b*NQ_+gq)*ld + h*DH_ + c8);
        *(short8*)(Qs + r*36 + c8) = v;
    }
    for(int idx=tid; idx<304*4; idx+=256){
        int r=idx>>2, c8=(idx&3)*8;
        short8 v = {};
        if(r<NQ_) v = *(const short8*)(QKV + 256 + (size_t)(b*NQ_+r)*ld + h*DH_ + c8);
        *(short8*)(Ks + r*36 + c8) = v;
    }
    for(int idx=tid; idx<320*4; idx+=256){
        int r=idx>>2, c8=(idx&3)*8;
        short8 v = {};
        if(r<NQ_) v = *(const short8*)(QKV + 512 + (size_t)(b*NQ_+r)*ld + h*DH_ + c8);
        #pragma unroll
        for(int j=0;j<8;j++) Vts[(c8+j)*324+r] = v[j];
    }
    __syncthreads();

    int lane = tid&63, wave = tid>>6;
    int lr = lane&15, lq = lane>>4;
    int mrow = wave*16;
    const float scale = 0.17677669529663687f;

    float4v acc[19];
    #pragma unroll
    for(int t=0;t<19;t++){ acc[t].x=0.f; acc[t].y=0.f; acc[t].z=0.f; acc[t].w=0.f; }
    short8 afrag = *(const short8*)(&Qs[(mrow+lr)*36 + lq*8]);
    #pragma unroll
    for(int t=0;t<19;t++){
        short8 bfrag = *(const short8*)(&Ks[(t*16+lr)*36 + lq*8]);
        acc[t] = __builtin_amdgcn_mfma_f32_16x16x32_bf16(afrag, bfrag, acc[t], 0,0,0);
    }
    __syncthreads();   // Qs/Ks dead; Ps overlay becomes writable

    for(int idx=tid; idx<64*16; idx+=256){
        int r=idx>>4, c=idx&15;
        Ps[r*324 + 304 + c]=0;
    }
    #pragma unroll
    for(int t=0;t<19;t++){
        #pragma unroll
        for(int r=0;r<4;r++) acc[t][r] *= scale;
    }
    if(lr>=12){
        #pragma unroll
        for(int r=0;r<4;r++) acc[18][r] = -1e30f;
    }
    float mx[4];
    #pragma unroll
    for(int r=0;r<4;r++){
        float m = acc[0][r];
        #pragma unroll
        for(int t=1;t<19;t++) m = fmaxf(m, acc[t][r]);
        m = fmaxf(m, __shfl_xor(m,1)); m = fmaxf(m, __shfl_xor(m,2));
        m = fmaxf(m, __shfl_xor(m,4)); m = fmaxf(m, __shfl_xor(m,8));
        mx[r]=m;
    }
    float sum[4] = {0.f,0.f,0.f,0.f};
    #pragma unroll
    for(int t=0;t<19;t++){
        #pragma unroll
        for(int r=0;r<4;r++){
            float p = __expf(acc[t][r]-mx[r]);
            acc[t][r]=p; sum[r]+=p;
        }
    }
    #pragma unroll
    for(int r=0;r<4;r++){
        float s = sum[r];
        s += __shfl_xor(s,1); s += __shfl_xor(s,2);
        s += __shfl_xor(s,4); s += __shfl_xor(s,8);
        sum[r] = 1.f/s;
    }
    #pragma unroll
    for(int t=0;t<19;t++){
        #pragma unroll
        for(int r=0;r<4;r++){
            Ps[(mrow + lq*4 + r)*324 + t*16 + lr] = f2bf(acc[t][r]*sum[r]);
        }
    }
    __syncthreads();
    float4v oacc[2];
    oacc[0].x=0.f;oacc[0].y=0.f;oacc[0].z=0.f;oacc[0].w=0.f;
    oacc[1]=oacc[0];
    #pragma unroll
    for(int kc=0;kc<10;kc++){
        short8 pa = *(const short8*)(&Ps[(mrow+lr)*324 + kc*32 + lq*8]);
        #pragma unroll
        for(int n=0;n<2;n++){
            short8 vb = *(const short8*)(&Vts[(n*16+lr)*324 + kc*32 + lq*8]);
            oacc[n] = __builtin_amdgcn_mfma_f32_16x16x32_bf16(pa, vb, oacc[n], 0,0,0);
        }
    }
    #pragma unroll
    for(int n=0;n<2;n++){
        #pragma unroll
        for(int r=0;r<4;r++){
            int gq = q0 + mrow + lq*4 + r;
            if(gq<NQ_)
                O[((size_t)(b*NQ_+gq))*D_ + h*DH_ + n*16 + lr] = f2bf(oacc[n][r]);
        }
    }
}

// ============== all-weights transpose f32[K][N] -> bf16[N][K] ==============
#define NTD 74
struct TD { const float* src; unsigned dstoff; int K, N, base; };
struct TAll { TD d[NTD]; };

__global__ __launch_bounds__(256) void transpose_all_kernel(TAll p, short* __restrict__ WTb){
    int blk = blockIdx.x;
    int di = 0;
    #pragma unroll 1
    for(int i=0;i<NTD;i++){ if(blk >= p.d[i].base) di = i; }
    TD d = p.d[di];
    int rel = blk - d.base;
    int ntx = (d.N+31)/32;
    int tn = (rel % ntx)*32, tk = (rel / ntx)*32;
    __shared__ float t[32][33];
    int tx = threadIdx.x&31, ty = threadIdx.x>>5;
    for(int i=0;i<32;i+=8){
        int k = tk+ty+i, n = tn+tx;
        t[ty+i][tx] = (k<d.K && n<d.N)? d.src[(size_t)k*d.N+n] : 0.f;
    }
    __syncthreads();
    short* out = WTb + d.dstoff;
    for(int i=0;i<32;i+=8){
        int n = tn+ty+i, k = tk+tx;
        if(n<d.N && k<d.K) out[(size_t)n*d.K+k] = f2bf(t[tx][ty+i]);
    }
}

// ---------------- small elementwise kernels ----------------
__global__ void copy_kernel(const float* __restrict__ a, float* __restrict__ o,
                            short* __restrict__ cb, int n){
    int i = blockIdx.x*blockDim.x+threadIdx.x;
    if(i<n){ float v=a[i]; o[i]=v; cb[i]=f2bf(v); }
}
__global__ void cvt_f32_bf16_kernel(const float* __restrict__ a, short* __restrict__ o, int n4){
    int i = blockIdx.x*blockDim.x+threadIdx.x;
    if(i<n4){
        float4v v = *(const float4v*)(a + (size_t)i*4);
        short4v h; h.x=f2bf(v.x); h.y=f2bf(v.y); h.z=f2bf(v.z); h.w=f2bf(v.w);
        *(short4v*)(o + (size_t)i*4) = h;
    }
}
__global__ void sigmoid_init_kernel(const float* __restrict__ a, float* __restrict__ o, int n){
    int i = blockIdx.x*blockDim.x+threadIdx.x;
    if(i<n){ float x=a[i]; o[i]=1.f/(1.f+expf(-x)); }
}
__global__ void write_out_kernel(const float* __restrict__ refd, const float* __restrict__ logits, float* __restrict__ out){
    int i = blockIdx.x*blockDim.x+threadIdx.x;
    if(i<BN_*4) out[i]=refd[i];
    else if(i<BN_*4+BN_*NCLS_) out[i]=logits[i-BN_*4];
}

// ---------------- layernorm with residual (t2 bf16), optional bf16 copy-out (+pos) ----------------
__global__ __launch_bounds__(256) void ln_residual_kernel(
    float* __restrict__ cur, const short* __restrict__ t2b,
    const float* __restrict__ g, const float* __restrict__ b,
    short* __restrict__ cb, const float* __restrict__ pa)
{
    int row = blockIdx.x; int c = threadIdx.x;
    size_t idx = (size_t)row*D_+c;
    float x = cur[idx] + bf2f(t2b[idx]);
    float v1 = x, v2 = x*x;
    #pragma unroll
    for(int o=32;o>0;o>>=1){ v1 += __shfl_down(v1,o,64); v2 += __shfl_down(v2,o,64); }
    __shared__ float s1[4], s2[4], st[2];
    int wid=c>>6, lane=c&63;
    if(lane==0){ s1[wid]=v1; s2[wid]=v2; }
    __syncthreads();
    if(c==0){
        float a=0,d=0;
        #pragma unroll
        for(int i=0;i<4;i++){a+=s1[i]; d+=s2[i];}
        st[0]=a/(float)D_; st[1]=d/(float)D_;
    }
    __syncthreads();
    float m=st[0], var=st[1]-m*m;
    float y = (x-m)*rsqrtf(var+1e-5f)*g[c] + b[c];
    cur[idx]=y;
    if(cb) cb[idx] = f2bf(pa? y + pa[idx] : y);
}

// ---------------- deformable sampling (fused attw softmax, bf16 out) ----------------
__global__ __launch_bounds__(256) void deform_sample_kernel(
    const float* __restrict__ refd, const float* __restrict__ oab,
    const bf16* __restrict__ value, short* __restrict__ outacc)
{
    int row = blockIdx.x; int b = row/NQ_;
    int tid = threadIdx.x; int h = tid>>5, c = tid&31;
    __shared__ float so[192], sa[96], sr[4];
    if(tid<192) so[tid]=oab[(size_t)row*288+tid];
    if(tid<96)  sa[tid]=oab[(size_t)row*288+192+tid];
    if(tid<4)   sr[tid]=refd[(size_t)row*4+tid];
    __syncthreads();
    if(tid<8){
        float* p = sa + tid*12;
        float m=-1e30f;
        #pragma unroll
        for(int i2=0;i2<12;i2++) m=fmaxf(m,p[i2]);
        float s=0.f;
        #pragma unroll
        for(int i2=0;i2<12;i2++){ float e=__expf(p[i2]-m); p[i2]=e; s+=e; }
        float inv=1.f/s;
        #pragma unroll
        for(int i2=0;i2<12;i2++) p[i2]*=inv;
    }
    __syncthreads();
    float cx=sr[0], cy=sr[1], rw=sr[2], rh=sr[3];
    const int HS[3]={80,40,20}, WS[3]={80,40,20}, ST[3]={0,6400,8000};
    float acc=0.f;
    const bf16* vb = value + (size_t)b*LM_*D_ + h*DH_ + c;
    for(int lv=0;lv<3;lv++){
        int Hl=HS[lv], Wl=WS[lv], st=ST[lv];
        #pragma unroll
        for(int pt=0;pt<4;pt++){
            int oi = ((h*3+lv)*4+pt)*2;
            float ox=so[oi], oy=so[oi+1];
            float wa=sa[h*12+lv*4+pt];
            float lx = cx + ox*0.25f*rw*0.5f;
            float ly = cy + oy*0.25f*rh*0.5f;
            float x = lx*(float)Wl - 0.5f, y = ly*(float)Hl - 0.5f;
            float x0f=floorf(x), y0f=floorf(y);
            float wx=x-x0f, wy=y-y0f;
            int x0=(int)x0f, y0=(int)y0f;
            #pragma unroll
            for(int dy=0;dy<2;dy++){
                #pragma unroll
                for(int dx=0;dx<2;dx++){
                    int xi=x0+dx, yi=y0+dy;
                    if(xi>=0 && xi<Wl && yi>=0 && yi<Hl){
                        float w = (dx? wx : 1.f-wx)*(dy? wy : 1.f-wy);
                        int lin = yi*Wl+xi;
                        acc += __bfloat162float(vb[(size_t)(st+lin)*D_]) * (w*wa);
                    }
                }
            }
        }
    }
    outacc[(size_t)row*D_+tid]=f2bf(acc);
}

// ---------------- host helpers ----------------
// tail GEMM dispatcher: TM=64, TN=64
static void g64x(const void*A, const void*A2, const void*A3, int nA2lim,
                 const short*WT, const float*b0, const float*b1, const float*b2,
                 int ns1, int ns2, void*C, int M,int K,int N,
                 bool abf16, bool relu, bool outbf, hipStream_t s){
    dim3 g((N+63)/64,(M+63)/64,1);
    #define CALLG(AB,RL,OB) mfma_gemm_kernel<64,64,AB,RL,OB><<<g,256,0,s>>>(A,A2,A3,nA2lim,WT,0,b0,b1,b2,ns1,ns2,0,C,0,M,K,N,0)
    if(abf16){
        if(relu){ if(outbf) CALLG(true,true,true);  else CALLG(true,true,false); }
        else    { if(outbf) CALLG(true,false,true); else CALLG(true,false,false); }
    } else {
        if(relu){ if(outbf) CALLG(false,true,true);  else CALLG(false,true,false); }
        else    { if(outbf) CALLG(false,false,true); else CALLG(false,false,false); }
    }
    #undef CALLG
}
static void g64b(const short*A, const short*WT, const float*b, void*C,
                 int M,int K,int N, hipStream_t s){
    g64x(A,nullptr,A,1<<30,WT,b,b,b,N,N+1,C,M,K,N,true,false,true,s);
}
static int ntiles(int K,int N){ return ((N+31)/32)*((K+31)/32); }

extern "C" void kernel_launch(void* const* d_in, const int* in_sizes, int n_in,
                              void* d_out, int out_size, void* d_ws, size_t ws_size,
                              hipStream_t stream) {
    const float* tgt   = (const float*)d_in[0];
    const float* rpu   = (const float*)d_in[1];
    const float* mem   = (const float*)d_in[2];
    const float* sa_wq = (const float*)d_in[3];
    const float* sa_wk = (const float*)d_in[4];
    const float* sa_wv = (const float*)d_in[5];
    const float* sa_wo = (const float*)d_in[6];
    const float* val_w = (const float*)d_in[7];
    const float* out_w = (const float*)d_in[8];
    const float* bb_w1 = (const float*)d_in[9];
    const float* bb_w2 = (const float*)d_in[10];
    const float* sa_bq = (const float*)d_in[11];
    const float* sa_bk = (const float*)d_in[12];
    const float* sa_bv = (const float*)d_in[13];
    const float* sa_bo = (const float*)d_in[14];
    const float* ln1_b = (const float*)d_in[15];
    const float* ln2_b = (const float*)d_in[16];
    const float* ln3_b = (const float*)d_in[17];
    const float* val_b = (const float*)d_in[18];
    const float* out_b = (const float*)d_in[19];
    const float* ffn_b2= (const float*)d_in[20];
    const float* bb_b1 = (const float*)d_in[21];
    const float* bb_b2 = (const float*)d_in[22];
    const float* ln1_g = (const float*)d_in[23];
    const float* ln2_g = (const float*)d_in[24];
    const float* ln3_g = (const float*)d_in[25];
    const float* off_w = (const float*)d_in[26];
    const float* off_b = (const float*)d_in[27];
    const float* attw_w= (const float*)d_in[28];
    const float* attw_b= (const float*)d_in[29];
    const float* ffn_w1= (const float*)d_in[30];
    const float* ffn_b1= (const float*)d_in[31];
    const float* ffn_w2= (const float*)d_in[32];
    const float* bb_w3 = (const float*)d_in[33];
    const float* bb_b3 = (const float*)d_in[34];
    const float* sc_w  = (const float*)d_in[35];
    const float* sc_b  = (const float*)d_in[36];
    const float* qp_w1 = (const float*)d_in[37];
    const float* qp_b1 = (const float*)d_in[38];
    const float* qp_w2 = (const float*)d_in[39];
    const float* qp_b2 = (const float*)d_in[40];

    const size_t BND = (size_t)BN_*D_;          // 1,228,800
    const size_t USZ = (size_t)BN_*DFF_;        // 4,915,200 floats (union)
    const size_t LMD = (size_t)BS_*LM_*D_;      // 34,406,400
    const size_t LSZ = 1122304;                 // WT shorts per layer

    float* ws   = (float*)d_ws;
    float* cur  = ws;
    float* pos  = cur + BND;
    float* refd = pos + BND;
    float* U    = refd + (size_t)BN_*4;
    short* tmp16 = (short*)(U + USZ);
    short* t216  = tmp16 + BND;
    short* WT    = t216 + BND;
    short* qp2T  = WT + 6*LSZ;
    short* scT   = qp2T + 131072;
    short* qpb   = scT + 20480;     // bf16(cur+pos), BND shorts
    short* X     = qpb + BND;
    // U aliases (phase-disjoint)
    short* QKVh16 = (short*)U;      // BN_*768 shorts = 7.4 MB
    float* offsb  = U;
    short* ffnh16 = (short*)U;
    float* logitsb= U;
    short* curb = tmp16;

    size_t offX = (size_t)((char*)X - (char*)d_ws);
    int vmode;
    if(ws_size >= offX + 7*LMD*2)      vmode = 3;
    else if(ws_size >= offX + 6*LMD*2) vmode = 2;
    else if(ws_size >= offX + 4*LMD)   vmode = 1;
    else                               vmode = 0;
    short* memT   = X;
    short* values = (vmode==3)? X + LMD : X;
    short* value1 = X + LMD;
    short* value0 = X;

    const int nBN_D = (int)BND;
    copy_kernel<<<(nBN_D+255)/256,256,0,stream>>>(tgt, cur, curb, nBN_D);
    sigmoid_init_kernel<<<(BN_*4+255)/256,256,0,stream>>>(rpu, refd, BN_*4);
    if(vmode==1 || vmode==3){
        int n4 = (int)(LMD/4);
        cvt_f32_bf16_kernel<<<(n4+255)/256,256,0,stream>>>(mem, memT, n4);
    }

    // ---- transpose ALL weights upfront (one launch) ----
    {
        TAll tp; int base=0; int di=0;
        const size_t offs[12] = { 0,65536,131072,196608,262144,327680,
                                  393216,442368,466944,729088,991232,1056768 };
        const int Ks[12] = { 256,256,256,256,256,256,256,256,256,1024,256,256 };
        const int Ns[12] = { 256,256,256,256,256,256,192,96,1024,256,256,256 };
        for(int l=0;l<NLAYERS_;l++){
            const float* srcs[12] = { sa_wq+(size_t)l*D_*D_, sa_wk+(size_t)l*D_*D_, sa_wv+(size_t)l*D_*D_,
                                      sa_wo+(size_t)l*D_*D_, val_w+(size_t)l*D_*D_, out_w+(size_t)l*D_*D_,
                                      off_w+(size_t)l*D_*192, attw_w+(size_t)l*D_*96,
                                      ffn_w1+(size_t)l*D_*DFF_, ffn_w2+(size_t)l*DFF_*D_,
                                      bb_w1+(size_t)l*D_*D_, bb_w2+(size_t)l*D_*D_ };
            for(int j=0;j<12;j++){
                tp.d[di] = { srcs[j], (unsigned)(l*LSZ + offs[j]), Ks[j], Ns[j], base };
                base += ntiles(Ks[j],Ns[j]); di++;
            }
        }
        tp.d[di] = { qp_w2, (unsigned)(6*LSZ), 512, 256, base }; base += ntiles(512,256); di++;
        tp.d[di] = { sc_w + (size_t)(NLAYERS_-1)*D_*NCLS_, (unsigned)(6*LSZ+131072), 256, 80, base }; base += ntiles(256,80); di++;
        transpose_all_kernel<<<base,256,0,stream>>>(tp, WT);
    }

    // ---- value projections (TM=128 pipelined, z-folded — verified config) ----
    if(vmode==3){
        dim3 g(12,1050,1);
        mfma_gemm_kernel<128,128,true,false,true><<<g,256,0,stream>>>(
            memT,nullptr,memT,1<<30, WT+262144, LSZ,
            val_b,val_b,val_b, 256,257, 256, values, LMD, BS_*LM_, D_, D_, 2);
    } else if(vmode==2){
        dim3 g(12,1050,1);
        mfma_gemm_kernel<128,128,false,false,true><<<g,256,0,stream>>>(
            mem,nullptr,mem,1<<30, WT+262144, LSZ,
            val_b,val_b,val_b, 256,257, 256, values, LMD, BS_*LM_, D_, D_, 2);
    }

    for(int i=0;i<NLAYERS_;i++){
        const bf16* value_i;
        if(vmode>=2) value_i = (const bf16*)(values + (size_t)i*LMD);
        else {
            dim3 g(2,1050,1);
            if(vmode==1){
                mfma_gemm_kernel<128,128,true,false,true><<<g,256,0,stream>>>(
                    memT,nullptr,memT,1<<30, WT+i*LSZ+262144, 0,
                    val_b+(size_t)i*D_,val_b,val_b, 256,257, 0, value1, 0, BS_*LM_, D_, D_, 0);
                value_i = (const bf16*)value1;
            } else {
                mfma_gemm_kernel<128,128,false,false,true><<<g,256,0,stream>>>(
                    mem,nullptr,mem,1<<30, WT+i*LSZ+262144, 0,
                    val_b+(size_t)i*D_,val_b,val_b, 256,257, 0, value0, 0, BS_*LM_, D_, D_, 0);
                value_i = (const bf16*)value0;
            }
        }
        // pos = MLP2(refd) ; qpb = bf16(cur+pos)
        pos_mlp_kernel<<<dim3(4,150),256,0,stream>>>(refd, qp_w1, qp_b1, qp2T, qp_b2,
                                                     cur, pos, qpb);
        // QKV: bf16-A — qpb for Q,K (n<512), curb for V; bf16 out
        g64x(qpb, nullptr, curb, 512, WT+i*LSZ,
             sa_bq+(size_t)i*D_, sa_bk+(size_t)i*D_, sa_bv+(size_t)i*D_, 256, 512,
             QKVh16, BN_, D_, 768, true,false,true, stream);
        {
            dim3 g((NQ_+63)/64, BS_*NHEAD_);
            fused_mha_kernel<<<g,256,0,stream>>>(QKVh16, tmp16);
        }
        g64b(tmp16, WT+i*LSZ+196608, sa_bo+(size_t)i*D_, t216, BN_, D_, D_, stream);
        // ln1: update cur, emit qpb = bf16(cur+pos) for off|attw
        ln_residual_kernel<<<BN_,256,0,stream>>>(cur, t216, ln1_g+(size_t)i*D_, ln1_b+(size_t)i*D_, qpb, pos);
        // deformable attention: off|attw projection, bf16-A on qpb
        g64x(qpb, nullptr, qpb, 1<<30, WT+i*LSZ+393216,
             off_b+(size_t)i*192, attw_b+(size_t)i*96, attw_b+(size_t)i*96, 192, 288,
             offsb, BN_, D_, 288, true,false,false, stream);
        deform_sample_kernel<<<BN_,256,0,stream>>>(refd, offsb, value_i, tmp16);
        g64b(tmp16, WT+i*LSZ+327680, out_b+(size_t)i*D_, t216, BN_, D_, D_, stream);
        ln_residual_kernel<<<BN_,256,0,stream>>>(cur, t216, ln2_g+(size_t)i*D_, ln2_b+(size_t)i*D_, curb, nullptr);
        // FFN
        g64x(curb,nullptr,curb,1<<30, WT+i*LSZ+466944, ffn_b1+(size_t)i*DFF_,ffn_b1,ffn_b1, DFF_,DFF_+1,
             ffnh16, BN_, D_, DFF_, true,true,true, stream);
        g64x(ffnh16,nullptr,ffnh16,1<<30, WT+i*LSZ+729088, ffn_b2+(size_t)i*D_,ffn_b2,ffn_b2, 256,257,
             t216, BN_, DFF_, D_, true,false,true, stream);
        ln_residual_kernel<<<BN_,256,0,stream>>>(cur, t216, ln3_g+(size_t)i*D_, ln3_b+(size_t)i*D_, curb, nullptr);
        // bbox head — single fused kernel
        bbox_head_kernel<<<BN_/16,256,0,stream>>>(curb,
            WT+i*LSZ+991232, bb_b1+(size_t)i*D_,
            WT+i*LSZ+1056768, bb_b2+(size_t)i*D_,
            bb_w3+(size_t)i*D_*4, bb_b3+(size_t)i*4, refd);
    }
    // final score GEMM: A = bf16 cur (curb from layer-5 ln3)
    g64x(curb,nullptr,curb,1<<30, scT, sc_b+(size_t)(NLAYERS_-1)*NCLS_,sc_b,sc_b, NCLS_,NCLS_+1,
         logitsb, BN_, D_, NCLS_, true,false,false, stream);
    int tot = BN_*4 + BN_*NCLS_;
    write_out_kernel<<<(tot+255)/256,256,0,stream>>>(refd, logitsb, (float*)d_out);
}